// Round 10
// baseline (2480.752 us; speedup 1.0000x reference)
//
#include <hip/hip_runtime.h>

// MsCorrBlock: B=8 T=8 C=256 PL=64 CR=16 H=W=56 HW=3136 NT=64 PS=7 KK=49
// Output dtype: FLOAT32 (205,520,896 B). BNI = 1/sqrt(1+1e-5).

#define MSC_BNI 0.9999950000374997f

static __device__ __forceinline__ float b2f(unsigned short h) {
  return __uint_as_float(((unsigned int)h) << 16);
}
static __device__ __forceinline__ unsigned short f2b(float f) {
  unsigned int u = __float_as_uint(f);
  u = u + 0x7FFFu + ((u >> 16) & 1u);   // round to nearest even
  return (unsigned short)(u >> 16);
}

// K0: weight transposes.  Wt1[c][o] = w1[o][c] (256x64).  Wt2[i][o][k] = w2[o][i][k].
__global__ __launch_bounds__(256) void k0_prep(
    const float* w1, const float* w2, float* Wt1, float* Wt2) {
  int idx = blockIdx.x * 256 + threadIdx.x;
  if (idx < 16384) {
    int c = idx >> 6, o = idx & 63;
    Wt1[idx] = w1[o * 256 + c];
  } else if (idx < 16384 + 36864) {
    int j = idx - 16384;
    int i = j / 576;
    int r = j - i * 576;
    int o = r / 9, k = r - o * 9;
    Wt2[j] = w2[o * 576 + i * 9 + k];
  }
}

// K1: per-channel temporal conv (K=1/3/5/7 by channel quarter), x fp32 -> A bf16.
__global__ __launch_bounds__(256, 8) void k1_tconv(
    const float* x, unsigned short* A,
    const float* w1, const float* w3, const float* w5, const float* w7) {
  int i = blockIdx.x * 256 + threadIdx.x;       // over 8*256*3136 = 6,422,528
  if (i >= 6422528) return;
  int hw = i % 3136;
  int bc = i / 3136;
  int c = bc & 255;
  int b = bc >> 8;
  int q = c >> 6, cc = c & 63;
  float wf[7];
#pragma unroll
  for (int k = 0; k < 7; k++) wf[k] = 0.f;
  if (q == 0) { wf[3] = w1[cc]; }
  else if (q == 1) { wf[2] = w3[cc*3]; wf[3] = w3[cc*3+1]; wf[4] = w3[cc*3+2]; }
  else if (q == 2) { wf[1] = w5[cc*5]; wf[2] = w5[cc*5+1]; wf[3] = w5[cc*5+2]; wf[4] = w5[cc*5+3]; wf[5] = w5[cc*5+4]; }
  else { wf[0] = w7[cc*7]; wf[1] = w7[cc*7+1]; wf[2] = w7[cc*7+2]; wf[3] = w7[cc*7+3]; wf[4] = w7[cc*7+4]; wf[5] = w7[cc*7+5]; wf[6] = w7[cc*7+6]; }

  int base = (b * 8 * 256 + c) * 3136 + hw;     // t=0 element
  int tstr = 256 * 3136;
  float xv[8];
#pragma unroll
  for (int t = 0; t < 8; t++) xv[t] = x[base + t * tstr];
#pragma unroll
  for (int t = 0; t < 8; t++) {
    float a = 0.f;
#pragma unroll
    for (int d = -3; d <= 3; d++) {
      int ts = t + d;
      if (ts >= 0 && ts < 8) a = fmaf(wf[d + 3], xv[ts], a);
    }
    A[base + t * tstr] = f2b(a);
  }
}

// K2: 1x1 conv 256->64 + BN + ReLU.  A bf16 -> R2 fp32.
// Thread = (n,hw) column: acc[64]; c streamed in chunks of 4 (loads in flight).
__global__ __launch_bounds__(256, 4) void k2_conv1(
    const unsigned short* A, float* R2,
    const float* Wt1, const float* g, const float* bb) {
  int i = blockIdx.x * 256 + threadIdx.x;       // over 200,704
  int n = i / 3136;
  int hw = i - n * 3136;
  const unsigned short* Ab = A + n * 256 * 3136 + hw;
  float acc[64];
#pragma unroll
  for (int o = 0; o < 64; o++) acc[o] = 0.f;
  for (int c0 = 0; c0 < 256; c0 += 4) {
    float a0 = b2f(Ab[(c0 + 0) * 3136]);
    float a1 = b2f(Ab[(c0 + 1) * 3136]);
    float a2 = b2f(Ab[(c0 + 2) * 3136]);
    float a3 = b2f(Ab[(c0 + 3) * 3136]);
    const float* wc = Wt1 + c0 * 64;            // wave-uniform, contiguous
#pragma unroll
    for (int o = 0; o < 64; o++) {
      float v = fmaf(wc[o], a0, acc[o]);
      v = fmaf(wc[64 + o], a1, v);
      v = fmaf(wc[128 + o], a2, v);
      acc[o] = fmaf(wc[192 + o], a3, v);
    }
  }
  float* Rb = R2 + n * 64 * 3136 + hw;
#pragma unroll
  for (int o = 0; o < 64; o++) {
    Rb[o * 3136] = fmaxf(fmaf(acc[o], g[o] * MSC_BNI, bb[o]), 0.f);
  }
}

// K3: 1x1 conv 64->16 + BN + ReLU.  R2 -> Y.  Column in registers.
__global__ __launch_bounds__(256, 4) void k3_conv21(
    const float* R2, float* Y,
    const float* w, const float* g, const float* bb) {
  int i = blockIdx.x * 256 + threadIdx.x;       // over 200,704
  int n = i / 3136;
  int hw = i - n * 3136;
  const float* Rb = R2 + n * 64 * 3136 + hw;
  float creg[64];
#pragma unroll
  for (int c = 0; c < 64; c++) creg[c] = Rb[c * 3136];
  float* Yb = Y + n * 16 * 3136 + hw;
  for (int o = 0; o < 16; o++) {
    const float* wr = w + o * 64;               // uniform, contiguous
    float a0 = 0.f, a1 = 0.f, a2 = 0.f, a3 = 0.f;
#pragma unroll
    for (int c = 0; c < 16; c++) {
      a0 = fmaf(wr[4*c+0], creg[4*c+0], a0);
      a1 = fmaf(wr[4*c+1], creg[4*c+1], a1);
      a2 = fmaf(wr[4*c+2], creg[4*c+2], a2);
      a3 = fmaf(wr[4*c+3], creg[4*c+3], a3);
    }
    float acc = (a0 + a1) + (a2 + a3);
    Yb[o * 3136] = fmaxf(fmaf(acc, g[o] * MSC_BNI, bb[o]), 0.f);
  }
}

// K4: 7x7-displacement correlation (vs t+1 clamped frame) /16 + BN + ReLU.
// Y (NT,16,HW) -> CO (NT,49,HW).  LDS ~38.8 KB.
__global__ __launch_bounds__(256) void k4_corr(
    const float* Y, float* CO, const float* g, const float* bb) {
  __shared__ float sb[10][16][62];              // rows h0-3..h0+6, ch, cols -3..58
  int n = blockIdx.x / 14;
  int h0 = (blockIdx.x % 14) * 4;
  int t = n & 7;
  int n2 = (t < 7) ? n + 1 : n;
  const float* Yb = Y + n2 * 16 * 3136;
  for (int idx = threadIdx.x; idx < 9920; idx += 256) {
    int r = idx / 992;
    int rem = idx - r * 992;
    int ch = rem / 62;
    int cl = rem - ch * 62;
    int gr = h0 - 3 + r, gc = cl - 3;
    float v = 0.f;
    if (gr >= 0 && gr < 56 && gc >= 0 && gc < 56)
      v = Yb[ch * 3136 + gr * 56 + gc];
    sb[r][ch][cl] = v;
  }
  __syncthreads();
  int pos = threadIdx.x;
  if (pos < 224) {
    int hl = pos / 56, wcol = pos - (pos / 56) * 56;
    float a[16];
    const float* Ya = Y + n * 16 * 3136 + (h0 + hl) * 56 + wcol;
#pragma unroll
    for (int c = 0; c < 16; c++) a[c] = Ya[c * 3136];
    float* Cp = CO + n * 49 * 3136 + (h0 + hl) * 56 + wcol;
    for (int di = 0; di < 7; di++) {
      for (int dj = 0; dj < 7; dj++) {
        float s = 0.f;
#pragma unroll
        for (int c = 0; c < 16; c++) s = fmaf(a[c], sb[hl + di][c][wcol + dj], s);
        int k = di * 7 + dj;
        float v = fmaf(s * 0.0625f, g[k] * MSC_BNI, bb[k]);
        Cp[k * 3136] = fmaxf(v, 0.f);
      }
    }
  }
}

// K6 (fused with K5): 3x3 conv 64->64 + BN + ReLU + O2(recomputed) -> C2.
// Block = (n, 2 output rows); LDS-staged input tile sIn[64][4][59] (60.4 KB).
// Thread = (column of 112, o-half of 32); oh = tid>>7 wave-uniform.
__global__ __launch_bounds__(256, 2) void k6_conv2(
    const float* R2, const float* CO, float* C2, const float* Wt2,
    const float* w22, const float* g23, const float* b23,
    const float* g2, const float* b2) {
  __shared__ float sIn[64][4][59];              // 60,416 B; global col = cl-1
  int n = blockIdx.x / 28;
  int h0 = (blockIdx.x % 28) * 2;
  const float* Rn = R2 + n * 64 * 3136;
  for (int idx = threadIdx.x; idx < 15104; idx += 256) {
    int ch = idx / 236;
    int rem = idx - ch * 236;
    int r = rem / 59, cl = rem - r * 59;
    int gr = h0 - 1 + r, gc = cl - 1;
    float v = 0.f;
    if (gr >= 0 && gr < 56 && gc >= 0 && gc < 56)
      v = Rn[ch * 3136 + gr * 56 + gc];
    sIn[ch][r][cl] = v;
  }
  __syncthreads();
  int lane = threadIdx.x & 127;                 // 112 active
  int oh = threadIdx.x >> 7;                    // 0..1, wave-uniform
  bool act = lane < 112;
  int row = act ? (lane / 56) : 0;              // 0..1
  int col = act ? (lane - (lane / 56) * 56) : 0;
  float acc[32];
#pragma unroll
  for (int o = 0; o < 32; o++) acc[o] = 0.f;
#pragma unroll 1
  for (int c = 0; c < 64; c++) {
    float v0 = sIn[c][row + 0][col + 0];
    float v1 = sIn[c][row + 0][col + 1];
    float v2 = sIn[c][row + 0][col + 2];
    float v3 = sIn[c][row + 1][col + 0];
    float v4 = sIn[c][row + 1][col + 1];
    float v5 = sIn[c][row + 1][col + 2];
    float v6 = sIn[c][row + 2][col + 0];
    float v7 = sIn[c][row + 2][col + 1];
    float v8 = sIn[c][row + 2][col + 2];
    const float* wc = Wt2 + c * 576 + oh * 288; // uniform, contiguous
#pragma unroll
    for (int o = 0; o < 32; o++) {
      const float* w9 = wc + o * 9;
      float s = fmaf(w9[0], v0, fmaf(w9[1], v1, w9[2] * v2));
      s = fmaf(w9[3], v3, fmaf(w9[4], v4, fmaf(w9[5], v5, s)));
      s = fmaf(w9[6], v6, fmaf(w9[7], v7, fmaf(w9[8], v8, s)));
      acc[o] += s;
    }
  }
  if (!act) return;
  int hw = (h0 + row) * 56 + col;
  // fused K5: O2[o] = relu(bn23(sum_c w22[o,c]*CO[c]) + R2[o]); R2 center from LDS
  float co[49];
  const float* pco = CO + n * 49 * 3136 + hw;
#pragma unroll
  for (int c = 0; c < 49; c++) co[c] = pco[c * 3136];
  float* Cb = C2 + n * 64 * 3136 + hw;
  for (int oi = 0; oi < 32; oi++) {
    int o = oh * 32 + oi;
    const float* wr = w22 + o * 49;             // uniform, contiguous
    float s = 0.f;
#pragma unroll
    for (int c = 0; c < 49; c++) s = fmaf(wr[c], co[c], s);
    float r2c = sIn[o][row + 1][col + 1];       // R2[o] at center
    float o2 = fmaxf(fmaf(s, g23[o] * MSC_BNI, b23[o]) + r2c, 0.f);
    float v = fmaxf(fmaf(acc[oi], g2[o] * MSC_BNI, b2[o]), 0.f) + o2;
    Cb[o * 3136] = v;
  }
}

// K7: 1x1 conv 64->256 + BN + x-residual + ReLU -> d_out FP32.
__global__ __launch_bounds__(256, 4) void k7_conv3(
    const float* C2, const float* x, float* outp,
    const float* w, const float* g, const float* bb) {
  int i = blockIdx.x * 256 + threadIdx.x;       // over 200,704
  int n = i / 3136;
  int hw = i - n * 3136;
  const float* Cb = C2 + n * 64 * 3136 + hw;
  float creg[64];
#pragma unroll
  for (int c = 0; c < 64; c++) creg[c] = Cb[c * 3136];
  const float* xb = x + n * 256 * 3136 + hw;
  float* ob = outp + n * 256 * 3136 + hw;
  for (int o = 0; o < 256; o++) {
    const float* wr = w + o * 64;               // uniform, contiguous
    float a0 = 0.f, a1 = 0.f, a2 = 0.f, a3 = 0.f;
#pragma unroll
    for (int c = 0; c < 16; c++) {
      a0 = fmaf(wr[4*c+0], creg[4*c+0], a0);
      a1 = fmaf(wr[4*c+1], creg[4*c+1], a1);
      a2 = fmaf(wr[4*c+2], creg[4*c+2], a2);
      a3 = fmaf(wr[4*c+3], creg[4*c+3], a3);
    }
    float acc = (a0 + a1) + (a2 + a3);
    float v = fmaxf(fmaf(acc, g[o] * MSC_BNI, bb[o]) + xb[o * 3136], 0.f);
    ob[o * 3136] = v;
  }
}

extern "C" void kernel_launch(void* const* d_in, const int* in_sizes, int n_in,
                              void* d_out, int out_size, void* d_ws, size_t ws_size,
                              hipStream_t stream) {
  const float* x        = (const float*)d_in[0];
  const float* w1       = (const float*)d_in[1];
  const float* w3       = (const float*)d_in[2];
  const float* w5       = (const float*)d_in[3];
  const float* w7       = (const float*)d_in[4];
  const float* w_conv1  = (const float*)d_in[5];
  const float* g1       = (const float*)d_in[6];
  const float* b1       = (const float*)d_in[7];
  const float* w_conv21 = (const float*)d_in[8];
  const float* g21      = (const float*)d_in[9];
  const float* b21      = (const float*)d_in[10];
  const float* g22      = (const float*)d_in[11];
  const float* b22      = (const float*)d_in[12];
  const float* w_conv22 = (const float*)d_in[13];
  const float* g23      = (const float*)d_in[14];
  const float* b23      = (const float*)d_in[15];
  const float* w_conv2  = (const float*)d_in[16];
  const float* g2       = (const float*)d_in[17];
  const float* b2       = (const float*)d_in[18];
  const float* w_conv3  = (const float*)d_in[19];
  const float* g3       = (const float*)d_in[20];
  const float* b3       = (const float*)d_in[21];

  // d_out (fp32, 205.5 MB) doubles as scratch:
  //   A   bf16 [0 .. 102,760,448)            K1 w, K2 r
  //   Y   fp32 [0 .. 12,845,056)             K3 w, K4 r   (A dead)
  //   CO  fp32 [12,845,056 .. 52,183,040)    K4 w, K6 r
  //   Wt1 fp32 [110,100,480 .. +65,536)      K0 w, K2 r
  //   Wt2 fp32 [110,166,016 .. +147,456)     K0 w, K6 r
  //   out fp32 (all)                         K7 w (everything above dead)
  // d_ws: R2 fp32 [0 .. 51,380,224), C2 fp32 [51,380,224 .. 102,760,448)
  char* ob = (char*)d_out;
  char* ws = (char*)d_ws;
  unsigned short* A   = (unsigned short*)ob;
  float*          Yv  = (float*)ob;
  float*          CO  = (float*)(ob + 12845056);
  float*          Wt1 = (float*)(ob + 110100480);
  float*          Wt2 = (float*)(ob + 110166016);
  float*          R2  = (float*)ws;
  float*          C2  = (float*)(ws + 51380224);

  k0_prep  <<<dim3(208),     dim3(256), 0, stream>>>(w_conv1, w_conv2, Wt1, Wt2);
  k1_tconv <<<dim3(25088),   dim3(256), 0, stream>>>(x, A, w1, w3, w5, w7);
  k2_conv1 <<<dim3(784),     dim3(256), 0, stream>>>(A, R2, Wt1, g1, b1);
  k3_conv21<<<dim3(784),     dim3(256), 0, stream>>>(R2, Yv, w_conv21, g21, b21);
  k4_corr  <<<dim3(64 * 14), dim3(256), 0, stream>>>(Yv, CO, g22, b22);
  k6_conv2 <<<dim3(64 * 28), dim3(256), 0, stream>>>(R2, CO, C2, Wt2, w_conv22, g23, b23, g2, b2);
  k7_conv3 <<<dim3(784),     dim3(256), 0, stream>>>(C2, x, (float*)d_out, w_conv3, g3, b3);
}

// Round 11
// 1224.526 us; speedup vs baseline: 2.0259x; 2.0259x over previous
//
#include <hip/hip_runtime.h>

// MsCorrBlock: B=8 T=8 C=256 PL=64 CR=16 H=W=56 HW=3136 NT=64 PS=7 KK=49
// Output dtype: FLOAT32 (205,520,896 B). BNI = 1/sqrt(1+1e-5).

#define MSC_BNI 0.9999950000374997f

typedef __attribute__((ext_vector_type(8))) short bf16x8;
typedef __attribute__((ext_vector_type(4))) float f32x4;

static __device__ __forceinline__ float b2f(unsigned short h) {
  return __uint_as_float(((unsigned int)h) << 16);
}
static __device__ __forceinline__ unsigned short f2b(float f) {
  unsigned int u = __float_as_uint(f);
  u = u + 0x7FFFu + ((u >> 16) & 1u);   // round to nearest even
  return (unsigned short)(u >> 16);
}

// K0: Wt1[c][o] = w1[o][c] (fp32, 256x64).  Wt2f = conv2 weights packed as
// bf16 MFMA A-fragments: [tap 9][kc 2][m 4][lane 64][e 8],
// value = w2[o = m*16+(lane&15)][c = kc*32+(lane>>4)*8+e][tap].
__global__ __launch_bounds__(256) void k0_prep(
    const float* w1, const float* w2, float* Wt1, unsigned short* Wt2f) {
  int idx = blockIdx.x * 256 + threadIdx.x;
  if (idx < 16384) {
    int c = idx >> 6, o = idx & 63;
    Wt1[idx] = w1[o * 256 + c];
  } else if (idx < 16384 + 36864) {
    int j = idx - 16384;
    int e = j & 7;
    int lane = (j >> 3) & 63;
    int m = (j >> 9) & 3;
    int kc = (j >> 11) & 1;
    int tap = j >> 12;                       // 0..8
    int o = m * 16 + (lane & 15);
    int c = kc * 32 + (lane >> 4) * 8 + e;
    Wt2f[j] = f2b(w2[(o * 64 + c) * 9 + tap]);
  }
}

// K1: per-channel temporal conv (K=1/3/5/7 by channel quarter), x fp32 -> A bf16.
__global__ __launch_bounds__(256, 8) void k1_tconv(
    const float* x, unsigned short* A,
    const float* w1, const float* w3, const float* w5, const float* w7) {
  int i = blockIdx.x * 256 + threadIdx.x;       // over 8*256*3136 = 6,422,528
  if (i >= 6422528) return;
  int hw = i % 3136;
  int bc = i / 3136;
  int c = bc & 255;
  int b = bc >> 8;
  int q = c >> 6, cc = c & 63;
  float wf[7];
#pragma unroll
  for (int k = 0; k < 7; k++) wf[k] = 0.f;
  if (q == 0) { wf[3] = w1[cc]; }
  else if (q == 1) { wf[2] = w3[cc*3]; wf[3] = w3[cc*3+1]; wf[4] = w3[cc*3+2]; }
  else if (q == 2) { wf[1] = w5[cc*5]; wf[2] = w5[cc*5+1]; wf[3] = w5[cc*5+2]; wf[4] = w5[cc*5+3]; wf[5] = w5[cc*5+4]; }
  else { wf[0] = w7[cc*7]; wf[1] = w7[cc*7+1]; wf[2] = w7[cc*7+2]; wf[3] = w7[cc*7+3]; wf[4] = w7[cc*7+4]; wf[5] = w7[cc*7+5]; wf[6] = w7[cc*7+6]; }

  int base = (b * 8 * 256 + c) * 3136 + hw;     // t=0 element
  int tstr = 256 * 3136;
  float xv[8];
#pragma unroll
  for (int t = 0; t < 8; t++) xv[t] = x[base + t * tstr];
#pragma unroll
  for (int t = 0; t < 8; t++) {
    float a = 0.f;
#pragma unroll
    for (int d = -3; d <= 3; d++) {
      int ts = t + d;
      if (ts >= 0 && ts < 8) a = fmaf(wf[d + 3], xv[ts], a);
    }
    A[base + t * tstr] = f2b(a);
  }
}

// K2: 1x1 conv 256->64 + BN + ReLU.  A bf16 -> R2 fp32 + R2b bf16.
__global__ __launch_bounds__(256, 4) void k2_conv1(
    const unsigned short* A, float* R2, unsigned short* R2b,
    const float* Wt1, const float* g, const float* bb) {
  int i = blockIdx.x * 256 + threadIdx.x;       // over 200,704
  int n = i / 3136;
  int hw = i - n * 3136;
  const unsigned short* Ab = A + n * 256 * 3136 + hw;
  float acc[64];
#pragma unroll
  for (int o = 0; o < 64; o++) acc[o] = 0.f;
  for (int c0 = 0; c0 < 256; c0 += 4) {
    float a0 = b2f(Ab[(c0 + 0) * 3136]);
    float a1 = b2f(Ab[(c0 + 1) * 3136]);
    float a2 = b2f(Ab[(c0 + 2) * 3136]);
    float a3 = b2f(Ab[(c0 + 3) * 3136]);
    const float* wc = Wt1 + c0 * 64;            // wave-uniform, contiguous
#pragma unroll
    for (int o = 0; o < 64; o++) {
      float v = fmaf(wc[o], a0, acc[o]);
      v = fmaf(wc[64 + o], a1, v);
      v = fmaf(wc[128 + o], a2, v);
      acc[o] = fmaf(wc[192 + o], a3, v);
    }
  }
  float* Rb = R2 + n * 64 * 3136 + hw;
  unsigned short* Rb2 = R2b + n * 64 * 3136 + hw;
#pragma unroll
  for (int o = 0; o < 64; o++) {
    float v = fmaxf(fmaf(acc[o], g[o] * MSC_BNI, bb[o]), 0.f);
    Rb[o * 3136] = v;
    Rb2[o * 3136] = f2b(v);
  }
}

// K3: 1x1 conv 64->16 + BN + ReLU.  R2 -> Y.  Column in registers.
__global__ __launch_bounds__(256, 4) void k3_conv21(
    const float* R2, float* Y,
    const float* w, const float* g, const float* bb) {
  int i = blockIdx.x * 256 + threadIdx.x;       // over 200,704
  int n = i / 3136;
  int hw = i - n * 3136;
  const float* Rb = R2 + n * 64 * 3136 + hw;
  float creg[64];
#pragma unroll
  for (int c = 0; c < 64; c++) creg[c] = Rb[c * 3136];
  float* Yb = Y + n * 16 * 3136 + hw;
  for (int o = 0; o < 16; o++) {
    const float* wr = w + o * 64;               // uniform, contiguous
    float a0 = 0.f, a1 = 0.f, a2 = 0.f, a3 = 0.f;
#pragma unroll
    for (int c = 0; c < 16; c++) {
      a0 = fmaf(wr[4*c+0], creg[4*c+0], a0);
      a1 = fmaf(wr[4*c+1], creg[4*c+1], a1);
      a2 = fmaf(wr[4*c+2], creg[4*c+2], a2);
      a3 = fmaf(wr[4*c+3], creg[4*c+3], a3);
    }
    float acc = (a0 + a1) + (a2 + a3);
    Yb[o * 3136] = fmaxf(fmaf(acc, g[o] * MSC_BNI, bb[o]), 0.f);
  }
}

// K4: 7x7-displacement correlation (vs t+1 clamped frame) /16 + BN + ReLU.
__global__ __launch_bounds__(256) void k4_corr(
    const float* Y, float* CO, const float* g, const float* bb) {
  __shared__ float sb[10][16][62];              // rows h0-3..h0+6, ch, cols -3..58
  int n = blockIdx.x / 14;
  int h0 = (blockIdx.x % 14) * 4;
  int t = n & 7;
  int n2 = (t < 7) ? n + 1 : n;
  const float* Yb = Y + n2 * 16 * 3136;
  for (int idx = threadIdx.x; idx < 9920; idx += 256) {
    int r = idx / 992;
    int rem = idx - r * 992;
    int ch = rem / 62;
    int cl = rem - ch * 62;
    int gr = h0 - 3 + r, gc = cl - 3;
    float v = 0.f;
    if (gr >= 0 && gr < 56 && gc >= 0 && gc < 56)
      v = Yb[ch * 3136 + gr * 56 + gc];
    sb[r][ch][cl] = v;
  }
  __syncthreads();
  int pos = threadIdx.x;
  if (pos < 224) {
    int hl = pos / 56, wcol = pos - (pos / 56) * 56;
    float a[16];
    const float* Ya = Y + n * 16 * 3136 + (h0 + hl) * 56 + wcol;
#pragma unroll
    for (int c = 0; c < 16; c++) a[c] = Ya[c * 3136];
    float* Cp = CO + n * 49 * 3136 + (h0 + hl) * 56 + wcol;
    for (int di = 0; di < 7; di++) {
      for (int dj = 0; dj < 7; dj++) {
        float s = 0.f;
#pragma unroll
        for (int c = 0; c < 16; c++) s = fmaf(a[c], sb[hl + di][c][wcol + dj], s);
        int k = di * 7 + dj;
        float v = fmaf(s * 0.0625f, g[k] * MSC_BNI, bb[k]);
        Cp[k * 3136] = fmaxf(v, 0.f);
      }
    }
  }
}

// K5: 1x1 conv 49->64 + BN + R2-add + ReLU -> O2 fp32. Column kernel.
__global__ __launch_bounds__(256, 4) void k5_conv22(
    const float* CO, const float* R2, float* O2,
    const float* w, const float* g, const float* bb) {
  int i = blockIdx.x * 256 + threadIdx.x;       // over 200,704
  int n = i / 3136;
  int hw = i - n * 3136;
  float co[49];
  const float* pco = CO + n * 49 * 3136 + hw;
#pragma unroll
  for (int c = 0; c < 49; c++) co[c] = pco[c * 3136];
  const float* Rb = R2 + n * 64 * 3136 + hw;
  float* Ob = O2 + n * 64 * 3136 + hw;
  for (int o = 0; o < 64; o++) {
    const float* wr = w + o * 49;               // uniform, contiguous
    float s = 0.f;
#pragma unroll
    for (int c = 0; c < 49; c++) s = fmaf(wr[c], co[c], s);
    Ob[o * 3136] = fmaxf(fmaf(s, g[o] * MSC_BNI, bb[o]) + Rb[o * 3136], 0.f);
  }
}

// K6: 3x3 conv 64->64 via MFMA implicit GEMM (bf16 in, fp32 acc) + BN + ReLU + O2.
// Block = (n, 4 output rows). LDS: input [6 rows][58 cols][64 c] bf16, XOR-swizzled.
// Wave w: 4 N-tiles (16 cols) x 4 M-tiles (16 o). Per (tap,kc): A = packed weight
// fragment (global 16B/lane), B = ds_read_b128 from swizzled LDS.
__global__ __launch_bounds__(256, 2) void k6_mfma(
    const unsigned short* R2b, const float* O2, float* C2,
    const unsigned short* Wt2f, const float* g2, const float* b2) {
  __shared__ unsigned short sIn[22272];         // 6*58*64, 44,544 B
  int n = blockIdx.x / 14;
  int h0 = (blockIdx.x % 14) * 4;
  const unsigned short* Rb = R2b + n * 64 * 3136;
  for (int idx = threadIdx.x; idx < 22272; idx += 256) {
    int c = idx / 348;
    int rem = idx - c * 348;
    int row = rem / 58, col = rem - row * 58;
    int gr = h0 - 1 + row, gc = col - 1;
    unsigned short v = 0;
    if (gr >= 0 && gr < 56 && gc >= 0 && gc < 56)
      v = Rb[c * 3136 + gr * 56 + gc];
    sIn[(((row * 58 + col) * 64) + c) ^ ((col & 7) << 3)] = v;
  }
  __syncthreads();
  int l = threadIdx.x & 63;
  int wv = threadIdx.x >> 6;                    // 0..3
  int l15 = l & 15, l4 = l >> 4;
  f32x4 acc[4][4];
#pragma unroll
  for (int m = 0; m < 4; m++)
#pragma unroll
    for (int t = 0; t < 4; t++) acc[m][t] = (f32x4){0.f, 0.f, 0.f, 0.f};

  for (int tap = 0; tap < 9; tap++) {
    int ky = tap / 3;
    int kx = tap - ky * 3;
    for (int kc = 0; kc < 2; kc++) {
      bf16x8 a[4];
#pragma unroll
      for (int m = 0; m < 4; m++)
        a[m] = *(const bf16x8*)(Wt2f + ((((tap * 2 + kc) * 4 + m) * 64 + l) << 3));
#pragma unroll
      for (int t = 0; t < 4; t++) {
        int ct = wv * 4 + t;
        int rowt = ct >> 2, col0 = (ct & 3) << 4;
        int lcol = col0 + l15 + kx;
        if (lcol > 57) lcol = 57;               // discarded cols read padding
        int us = ((((rowt + ky) * 58 + lcol) * 64) + kc * 32 + (l4 << 3))
                 ^ ((lcol & 7) << 3);
        bf16x8 b = *(const bf16x8*)(sIn + us);
#pragma unroll
        for (int m = 0; m < 4; m++)
          acc[m][t] = __builtin_amdgcn_mfma_f32_16x16x32_bf16(a[m], b, acc[m][t], 0, 0, 0);
      }
    }
  }

#pragma unroll
  for (int t = 0; t < 4; t++) {
    int ct = wv * 4 + t;
    int rowt = ct >> 2, col0 = (ct & 3) << 4;
    int cc = col0 + l15;
    if (cc < 56) {
      int hw = (h0 + rowt) * 56 + cc;
      int base = n * 64 * 3136 + hw;
#pragma unroll
      for (int m = 0; m < 4; m++) {
#pragma unroll
        for (int r = 0; r < 4; r++) {
          int o = m * 16 + l4 * 4 + r;
          int off = base + o * 3136;
          float v = fmaxf(fmaf(acc[m][t][r], g2[o] * MSC_BNI, b2[o]), 0.f) + O2[off];
          C2[off] = v;
        }
      }
    }
  }
}

// K7: 1x1 conv 64->256 + BN + x-residual + ReLU -> d_out FP32.
__global__ __launch_bounds__(256, 4) void k7_conv3(
    const float* C2, const float* x, float* outp,
    const float* w, const float* g, const float* bb) {
  int i = blockIdx.x * 256 + threadIdx.x;       // over 200,704
  int n = i / 3136;
  int hw = i - n * 3136;
  const float* Cb = C2 + n * 64 * 3136 + hw;
  float creg[64];
#pragma unroll
  for (int c = 0; c < 64; c++) creg[c] = Cb[c * 3136];
  const float* xb = x + n * 256 * 3136 + hw;
  float* ob = outp + n * 256 * 3136 + hw;
  for (int o = 0; o < 256; o++) {
    const float* wr = w + o * 64;               // uniform, contiguous
    float a0 = 0.f, a1 = 0.f, a2 = 0.f, a3 = 0.f;
#pragma unroll
    for (int c = 0; c < 16; c++) {
      a0 = fmaf(wr[4*c+0], creg[4*c+0], a0);
      a1 = fmaf(wr[4*c+1], creg[4*c+1], a1);
      a2 = fmaf(wr[4*c+2], creg[4*c+2], a2);
      a3 = fmaf(wr[4*c+3], creg[4*c+3], a3);
    }
    float acc = (a0 + a1) + (a2 + a3);
    float v = fmaxf(fmaf(acc, g[o] * MSC_BNI, bb[o]) + xb[o * 3136], 0.f);
    ob[o * 3136] = v;
  }
}

extern "C" void kernel_launch(void* const* d_in, const int* in_sizes, int n_in,
                              void* d_out, int out_size, void* d_ws, size_t ws_size,
                              hipStream_t stream) {
  const float* x        = (const float*)d_in[0];
  const float* w1       = (const float*)d_in[1];
  const float* w3       = (const float*)d_in[2];
  const float* w5       = (const float*)d_in[3];
  const float* w7       = (const float*)d_in[4];
  const float* w_conv1  = (const float*)d_in[5];
  const float* g1       = (const float*)d_in[6];
  const float* b1       = (const float*)d_in[7];
  const float* w_conv21 = (const float*)d_in[8];
  const float* g21      = (const float*)d_in[9];
  const float* b21      = (const float*)d_in[10];
  const float* g22      = (const float*)d_in[11];
  const float* b22      = (const float*)d_in[12];
  const float* w_conv22 = (const float*)d_in[13];
  const float* g23      = (const float*)d_in[14];
  const float* b23      = (const float*)d_in[15];
  const float* w_conv2  = (const float*)d_in[16];
  const float* g2       = (const float*)d_in[17];
  const float* b2       = (const float*)d_in[18];
  const float* w_conv3  = (const float*)d_in[19];
  const float* g3       = (const float*)d_in[20];
  const float* b3       = (const float*)d_in[21];

  // d_out (fp32, 205,520,896 B) scratch map (all dead before K7's full rewrite):
  //   A    bf16 [0 .. 102,760,448)            K1 w, K2 r
  //   Y    fp32 [0 .. 12,845,056)             K3 w, K4 r   (A dead)
  //   CO   fp32 [12,845,056 .. 52,183,040)    K4 w, K5 r
  //   O2   fp32 [52,183,040 .. 103,563,264)   K5 w, K6 r
  //   R2b  bf16 [103,563,264 .. 129,253,376)  K2 w, K6 r
  //   Wt1  fp32 [134,217,728 .. +65,536)      K0 w, K2 r
  //   Wt2f bf16 [134,283,264 .. +73,728)      K0 w, K6 r
  // d_ws: R2 fp32 [0 .. 51,380,224), C2 fp32 [51,380,224 .. 102,760,448)
  char* ob = (char*)d_out;
  char* ws = (char*)d_ws;
  unsigned short* A    = (unsigned short*)ob;
  float*          Yv   = (float*)ob;
  float*          CO   = (float*)(ob + 12845056);
  float*          O2   = (float*)(ob + 52183040);
  unsigned short* R2b  = (unsigned short*)(ob + 103563264);
  float*          Wt1  = (float*)(ob + 134217728);
  unsigned short* Wt2f = (unsigned short*)(ob + 134283264);
  float*          R2   = (float*)ws;
  float*          C2   = (float*)(ws + 51380224);

  k0_prep  <<<dim3(208),     dim3(256), 0, stream>>>(w_conv1, w_conv2, Wt1, Wt2f);
  k1_tconv <<<dim3(25088),   dim3(256), 0, stream>>>(x, A, w1, w3, w5, w7);
  k2_conv1 <<<dim3(784),     dim3(256), 0, stream>>>(A, R2, R2b, Wt1, g1, b1);
  k3_conv21<<<dim3(784),     dim3(256), 0, stream>>>(R2, Yv, w_conv21, g21, b21);
  k4_corr  <<<dim3(64 * 14), dim3(256), 0, stream>>>(Yv, CO, g22, b22);
  k5_conv22<<<dim3(784),     dim3(256), 0, stream>>>(CO, R2, O2, w_conv22, g23, b23);
  k6_mfma  <<<dim3(64 * 14), dim3(256), 0, stream>>>(R2b, O2, C2, Wt2f, g2, b2);
  k7_conv3 <<<dim3(784),     dim3(256), 0, stream>>>(C2, x, (float*)d_out, w_conv3, g3, b3);
}

// Round 12
// 676.849 us; speedup vs baseline: 3.6651x; 1.8092x over previous
//
#include <hip/hip_runtime.h>

// MsCorrBlock: B=8 T=8 C=256 PL=64 CR=16 H=W=56 HW=3136 NT=64 PS=7 KK=49
// Output dtype: FLOAT32 (205,520,896 B). BNI = 1/sqrt(1+1e-5).

#define MSC_BNI 0.9999950000374997f

typedef __attribute__((ext_vector_type(8))) short bf16x8;
typedef __attribute__((ext_vector_type(4))) float f32x4;

static __device__ __forceinline__ float b2f(unsigned short h) {
  return __uint_as_float(((unsigned int)h) << 16);
}
static __device__ __forceinline__ unsigned short f2b(float f) {
  unsigned int u = __float_as_uint(f);
  u = u + 0x7FFFu + ((u >> 16) & 1u);   // round to nearest even
  return (unsigned short)(u >> 16);
}

// K0: Wt1[c][o] = w1[o][c] (fp32).  Wt2f = conv2 weights as bf16 MFMA A-frags
// [tap9][kc2][m4][lane64][e8].  Wt3f = conv3 weights as bf16 A-frags
// [kc2][m16][lane64][e8], value = w3[o = m*16+(l&15)][c = kc*32+(l>>4)*8+e].
__global__ __launch_bounds__(256) void k0_prep(
    const float* w1, const float* w2, const float* w3,
    float* Wt1, unsigned short* Wt2f, unsigned short* Wt3f) {
  int idx = blockIdx.x * 256 + threadIdx.x;
  if (idx < 16384) {
    int c = idx >> 6, o = idx & 63;
    Wt1[idx] = w1[o * 256 + c];
  } else if (idx < 16384 + 36864) {
    int j = idx - 16384;
    int e = j & 7;
    int lane = (j >> 3) & 63;
    int m = (j >> 9) & 3;
    int kc = (j >> 11) & 1;
    int tap = j >> 12;                       // 0..8
    int o = m * 16 + (lane & 15);
    int c = kc * 32 + (lane >> 4) * 8 + e;
    Wt2f[j] = f2b(w2[(o * 64 + c) * 9 + tap]);
  } else if (idx < 16384 + 36864 + 16384) {
    int j = idx - 16384 - 36864;
    int e = j & 7;
    int lane = (j >> 3) & 63;
    int m = (j >> 9) & 15;
    int kc = j >> 13;                        // 0..1
    int o = m * 16 + (lane & 15);
    int c = kc * 32 + (lane >> 4) * 8 + e;
    Wt3f[j] = f2b(w3[o * 64 + c]);
  }
}

// K1: per-channel temporal conv (K=1/3/5/7 by channel quarter), x fp32 -> A bf16.
__global__ __launch_bounds__(256, 8) void k1_tconv(
    const float* x, unsigned short* A,
    const float* w1, const float* w3, const float* w5, const float* w7) {
  int i = blockIdx.x * 256 + threadIdx.x;       // over 8*256*3136 = 6,422,528
  if (i >= 6422528) return;
  int hw = i % 3136;
  int bc = i / 3136;
  int c = bc & 255;
  int b = bc >> 8;
  int q = c >> 6, cc = c & 63;
  float wf[7];
#pragma unroll
  for (int k = 0; k < 7; k++) wf[k] = 0.f;
  if (q == 0) { wf[3] = w1[cc]; }
  else if (q == 1) { wf[2] = w3[cc*3]; wf[3] = w3[cc*3+1]; wf[4] = w3[cc*3+2]; }
  else if (q == 2) { wf[1] = w5[cc*5]; wf[2] = w5[cc*5+1]; wf[3] = w5[cc*5+2]; wf[4] = w5[cc*5+3]; wf[5] = w5[cc*5+4]; }
  else { wf[0] = w7[cc*7]; wf[1] = w7[cc*7+1]; wf[2] = w7[cc*7+2]; wf[3] = w7[cc*7+3]; wf[4] = w7[cc*7+4]; wf[5] = w7[cc*7+5]; wf[6] = w7[cc*7+6]; }

  int base = (b * 8 * 256 + c) * 3136 + hw;     // t=0 element
  int tstr = 256 * 3136;
  float xv[8];
#pragma unroll
  for (int t = 0; t < 8; t++) xv[t] = x[base + t * tstr];
#pragma unroll
  for (int t = 0; t < 8; t++) {
    float a = 0.f;
#pragma unroll
    for (int d = -3; d <= 3; d++) {
      int ts = t + d;
      if (ts >= 0 && ts < 8) a = fmaf(wf[d + 3], xv[ts], a);
    }
    A[base + t * tstr] = f2b(a);
  }
}

// K2: 1x1 conv 256->64 + BN + ReLU.  A bf16 -> R2 fp32 + R2b bf16.
__global__ __launch_bounds__(256, 2) void k2_conv1(
    const unsigned short* A, float* R2, unsigned short* R2b,
    const float* Wt1, const float* g, const float* bb) {
  int i = blockIdx.x * 256 + threadIdx.x;       // over 200,704
  int n = i / 3136;
  int hw = i - n * 3136;
  const unsigned short* Ab = A + n * 256 * 3136 + hw;
  float acc[64];
#pragma unroll
  for (int o = 0; o < 64; o++) acc[o] = 0.f;
  for (int c0 = 0; c0 < 256; c0 += 4) {
    float a0 = b2f(Ab[(c0 + 0) * 3136]);
    float a1 = b2f(Ab[(c0 + 1) * 3136]);
    float a2 = b2f(Ab[(c0 + 2) * 3136]);
    float a3 = b2f(Ab[(c0 + 3) * 3136]);
    const float* wc = Wt1 + c0 * 64;            // wave-uniform, contiguous
#pragma unroll
    for (int o = 0; o < 64; o++) {
      float v = fmaf(wc[o], a0, acc[o]);
      v = fmaf(wc[64 + o], a1, v);
      v = fmaf(wc[128 + o], a2, v);
      acc[o] = fmaf(wc[192 + o], a3, v);
    }
  }
  float* Rb = R2 + n * 64 * 3136 + hw;
  unsigned short* Rb2 = R2b + n * 64 * 3136 + hw;
#pragma unroll
  for (int o = 0; o < 64; o++) {
    float v = fmaxf(fmaf(acc[o], g[o] * MSC_BNI, bb[o]), 0.f);
    Rb[o * 3136] = v;
    Rb2[o * 3136] = f2b(v);
  }
}

// K3: 1x1 conv 64->16 + BN + ReLU.  R2 -> Y.  Column in registers.
__global__ __launch_bounds__(256, 2) void k3_conv21(
    const float* R2, float* Y,
    const float* w, const float* g, const float* bb) {
  int i = blockIdx.x * 256 + threadIdx.x;       // over 200,704
  int n = i / 3136;
  int hw = i - n * 3136;
  const float* Rb = R2 + n * 64 * 3136 + hw;
  float creg[64];
#pragma unroll
  for (int c = 0; c < 64; c++) creg[c] = Rb[c * 3136];
  float* Yb = Y + n * 16 * 3136 + hw;
  for (int o = 0; o < 16; o++) {
    const float* wr = w + o * 64;               // uniform, contiguous
    float a0 = 0.f, a1 = 0.f, a2 = 0.f, a3 = 0.f;
#pragma unroll
    for (int c = 0; c < 16; c++) {
      a0 = fmaf(wr[4*c+0], creg[4*c+0], a0);
      a1 = fmaf(wr[4*c+1], creg[4*c+1], a1);
      a2 = fmaf(wr[4*c+2], creg[4*c+2], a2);
      a3 = fmaf(wr[4*c+3], creg[4*c+3], a3);
    }
    float acc = (a0 + a1) + (a2 + a3);
    Yb[o * 3136] = fmaxf(fmaf(acc, g[o] * MSC_BNI, bb[o]), 0.f);
  }
}

// K4: 7x7-displacement correlation (vs t+1 clamped frame) /16 + BN + ReLU.
__global__ __launch_bounds__(256) void k4_corr(
    const float* Y, float* CO, const float* g, const float* bb) {
  __shared__ float sb[10][16][62];              // rows h0-3..h0+6, ch, cols -3..58
  int n = blockIdx.x / 14;
  int h0 = (blockIdx.x % 14) * 4;
  int t = n & 7;
  int n2 = (t < 7) ? n + 1 : n;
  const float* Yb = Y + n2 * 16 * 3136;
  for (int idx = threadIdx.x; idx < 9920; idx += 256) {
    int r = idx / 992;
    int rem = idx - r * 992;
    int ch = rem / 62;
    int cl = rem - ch * 62;
    int gr = h0 - 3 + r, gc = cl - 3;
    float v = 0.f;
    if (gr >= 0 && gr < 56 && gc >= 0 && gc < 56)
      v = Yb[ch * 3136 + gr * 56 + gc];
    sb[r][ch][cl] = v;
  }
  __syncthreads();
  int pos = threadIdx.x;
  if (pos < 224) {
    int hl = pos / 56, wcol = pos - (pos / 56) * 56;
    float a[16];
    const float* Ya = Y + n * 16 * 3136 + (h0 + hl) * 56 + wcol;
#pragma unroll
    for (int c = 0; c < 16; c++) a[c] = Ya[c * 3136];
    float* Cp = CO + n * 49 * 3136 + (h0 + hl) * 56 + wcol;
    for (int di = 0; di < 7; di++) {
      for (int dj = 0; dj < 7; dj++) {
        float s = 0.f;
#pragma unroll
        for (int c = 0; c < 16; c++) s = fmaf(a[c], sb[hl + di][c][wcol + dj], s);
        int k = di * 7 + dj;
        float v = fmaf(s * 0.0625f, g[k] * MSC_BNI, bb[k]);
        Cp[k * 3136] = fmaxf(v, 0.f);
      }
    }
  }
}

// K5: 1x1 conv 49->64 + BN + R2-add + ReLU -> O2 fp32. Column kernel.
__global__ __launch_bounds__(256, 2) void k5_conv22(
    const float* CO, const float* R2, float* O2,
    const float* w, const float* g, const float* bb) {
  int i = blockIdx.x * 256 + threadIdx.x;       // over 200,704
  int n = i / 3136;
  int hw = i - n * 3136;
  float co[49];
  const float* pco = CO + n * 49 * 3136 + hw;
#pragma unroll
  for (int c = 0; c < 49; c++) co[c] = pco[c * 3136];
  const float* Rb = R2 + n * 64 * 3136 + hw;
  float* Ob = O2 + n * 64 * 3136 + hw;
  for (int o = 0; o < 64; o++) {
    const float* wr = w + o * 49;               // uniform, contiguous
    float s = 0.f;
#pragma unroll
    for (int c = 0; c < 49; c++) s = fmaf(wr[c], co[c], s);
    Ob[o * 3136] = fmaxf(fmaf(s, g[o] * MSC_BNI, bb[o]) + Rb[o * 3136], 0.f);
  }
}

// K6: 3x3 conv 64->64 via MFMA implicit GEMM + BN + ReLU + O2 -> C2b bf16.
__global__ __launch_bounds__(256, 2) void k6_mfma(
    const unsigned short* R2b, const float* O2, unsigned short* C2b,
    const unsigned short* Wt2f, const float* g2, const float* b2) {
  __shared__ unsigned short sIn[22272];         // 6*58*64, 44,544 B
  int n = blockIdx.x / 14;
  int h0 = (blockIdx.x % 14) * 4;
  const unsigned short* Rb = R2b + n * 64 * 3136;
  for (int idx = threadIdx.x; idx < 22272; idx += 256) {
    int c = idx / 348;
    int rem = idx - c * 348;
    int row = rem / 58, col = rem - row * 58;
    int gr = h0 - 1 + row, gc = col - 1;
    unsigned short v = 0;
    if (gr >= 0 && gr < 56 && gc >= 0 && gc < 56)
      v = Rb[c * 3136 + gr * 56 + gc];
    sIn[(((row * 58 + col) * 64) + c) ^ ((col & 7) << 3)] = v;
  }
  __syncthreads();
  int l = threadIdx.x & 63;
  int wv = threadIdx.x >> 6;                    // 0..3
  int l15 = l & 15, l4 = l >> 4;
  f32x4 acc[4][4];
#pragma unroll
  for (int m = 0; m < 4; m++)
#pragma unroll
    for (int t = 0; t < 4; t++) acc[m][t] = (f32x4){0.f, 0.f, 0.f, 0.f};

  for (int tap = 0; tap < 9; tap++) {
    int ky = tap / 3;
    int kx = tap - ky * 3;
    for (int kc = 0; kc < 2; kc++) {
      bf16x8 a[4];
#pragma unroll
      for (int m = 0; m < 4; m++)
        a[m] = *(const bf16x8*)(Wt2f + ((((tap * 2 + kc) * 4 + m) * 64 + l) << 3));
#pragma unroll
      for (int t = 0; t < 4; t++) {
        int ct = wv * 4 + t;
        int rowt = ct >> 2, col0 = (ct & 3) << 4;
        int lcol = col0 + l15 + kx;
        if (lcol > 57) lcol = 57;               // discarded cols read padding
        int us = ((((rowt + ky) * 58 + lcol) * 64) + kc * 32 + (l4 << 3))
                 ^ ((lcol & 7) << 3);
        bf16x8 b = *(const bf16x8*)(sIn + us);
#pragma unroll
        for (int m = 0; m < 4; m++)
          acc[m][t] = __builtin_amdgcn_mfma_f32_16x16x32_bf16(a[m], b, acc[m][t], 0, 0, 0);
      }
    }
  }

#pragma unroll
  for (int t = 0; t < 4; t++) {
    int ct = wv * 4 + t;
    int rowt = ct >> 2, col0 = (ct & 3) << 4;
    int cc = col0 + l15;
    if (cc < 56) {
      int hw = (h0 + rowt) * 56 + cc;
      int base = n * 64 * 3136 + hw;
#pragma unroll
      for (int m = 0; m < 4; m++) {
#pragma unroll
        for (int r = 0; r < 4; r++) {
          int o = m * 16 + l4 * 4 + r;
          int off = base + o * 3136;
          float v = fmaxf(fmaf(acc[m][t][r], g2[o] * MSC_BNI, b2[o]), 0.f) + O2[off];
          C2b[off] = f2b(v);
        }
      }
    }
  }
}

// K7: 1x1 conv 64->256 via MFMA GEMM + BN + x-residual + ReLU -> d_out fp32.
// Block = (n, 64 hw cols). LDS: C2b tile [col 64][c 64] bf16, XOR-swizzled.
// Wave wv: M-tiles wv*4..+3 (o = 64 per wave), 4 N-tiles, K=64 (2 kc).
__global__ __launch_bounds__(256, 2) void k7_mfma(
    const unsigned short* C2b, const float* x, float* outp,
    const unsigned short* Wt3f, const float* g, const float* bb) {
  __shared__ unsigned short sC[4096];           // 8 KB
  int n = blockIdx.x / 49;
  int hw0 = (blockIdx.x % 49) * 64;
  const unsigned short* Cb = C2b + n * 64 * 3136 + hw0;
  for (int idx = threadIdx.x; idx < 4096; idx += 256) {
    int c = idx >> 6, col = idx & 63;
    sC[(col * 64 + c) ^ ((col & 7) << 3)] = Cb[c * 3136 + col];
  }
  __syncthreads();
  int l = threadIdx.x & 63;
  int wv = threadIdx.x >> 6;                    // 0..3
  int l15 = l & 15, l4 = l >> 4;
  f32x4 acc[4][4];
#pragma unroll
  for (int m = 0; m < 4; m++)
#pragma unroll
    for (int t = 0; t < 4; t++) acc[m][t] = (f32x4){0.f, 0.f, 0.f, 0.f};

#pragma unroll
  for (int kc = 0; kc < 2; kc++) {
    bf16x8 a[4];
#pragma unroll
    for (int m = 0; m < 4; m++)
      a[m] = *(const bf16x8*)(Wt3f + (((kc * 16 + wv * 4 + m) * 64 + l) << 3));
#pragma unroll
    for (int t = 0; t < 4; t++) {
      int us = (((t * 16 + l15) * 64) + kc * 32 + (l4 << 3)) ^ ((l15 & 7) << 3);
      bf16x8 b = *(const bf16x8*)(sC + us);
#pragma unroll
      for (int m = 0; m < 4; m++)
        acc[m][t] = __builtin_amdgcn_mfma_f32_16x16x32_bf16(a[m], b, acc[m][t], 0, 0, 0);
    }
  }

#pragma unroll
  for (int t = 0; t < 4; t++) {
    int col = hw0 + t * 16 + l15;
#pragma unroll
    for (int m = 0; m < 4; m++) {
      int mt = wv * 4 + m;
#pragma unroll
      for (int r = 0; r < 4; r++) {
        int o = mt * 16 + l4 * 4 + r;
        int off = (n * 256 + o) * 3136 + col;
        float v = fmaxf(fmaf(acc[m][t][r], g[o] * MSC_BNI, bb[o]) + x[off], 0.f);
        outp[off] = v;
      }
    }
  }
}

extern "C" void kernel_launch(void* const* d_in, const int* in_sizes, int n_in,
                              void* d_out, int out_size, void* d_ws, size_t ws_size,
                              hipStream_t stream) {
  const float* x        = (const float*)d_in[0];
  const float* w1       = (const float*)d_in[1];
  const float* w3       = (const float*)d_in[2];
  const float* w5       = (const float*)d_in[3];
  const float* w7       = (const float*)d_in[4];
  const float* w_conv1  = (const float*)d_in[5];
  const float* g1       = (const float*)d_in[6];
  const float* b1       = (const float*)d_in[7];
  const float* w_conv21 = (const float*)d_in[8];
  const float* g21      = (const float*)d_in[9];
  const float* b21      = (const float*)d_in[10];
  const float* g22      = (const float*)d_in[11];
  const float* b22      = (const float*)d_in[12];
  const float* w_conv22 = (const float*)d_in[13];
  const float* g23      = (const float*)d_in[14];
  const float* b23      = (const float*)d_in[15];
  const float* w_conv2  = (const float*)d_in[16];
  const float* g2       = (const float*)d_in[17];
  const float* b2       = (const float*)d_in[18];
  const float* w_conv3  = (const float*)d_in[19];
  const float* g3       = (const float*)d_in[20];
  const float* b3       = (const float*)d_in[21];

  // d_out (fp32, 205,520,896 B) scratch map (all dead before K7's full rewrite):
  //   A    bf16 [0 .. 102,760,448)            K1 w, K2 r
  //   Y    fp32 [0 .. 12,845,056)             K3 w, K4 r   (A dead)
  //   CO   fp32 [12,845,056 .. 52,183,040)    K4 w, K5 r
  //   O2   fp32 [52,183,040 .. 103,563,264)   K5 w, K6 r
  //   R2b  bf16 [103,563,264 .. 129,253,376)  K2 w, K6 r
  //   Wt1  fp32 [134,217,728 .. +65,536)      K0 w, K2 r
  //   Wt2f bf16 [134,283,264 .. +73,728)      K0 w, K6 r
  // d_ws (>= 102,760,448 B):
  //   R2   fp32 [0 .. 51,380,224)             K2 w; K3,K5 r
  //   C2b  bf16 [51,380,224 .. 77,070,336)    K6 w, K7 r
  //   Wt3f bf16 [77,070,336 .. +32,768)       K0 w, K7 r  (K7 reads while writing
  //                                           d_out, so it must live in d_ws)
  char* ob = (char*)d_out;
  char* ws = (char*)d_ws;
  unsigned short* A    = (unsigned short*)ob;
  float*          Yv   = (float*)ob;
  float*          CO   = (float*)(ob + 12845056);
  float*          O2   = (float*)(ob + 52183040);
  unsigned short* R2b  = (unsigned short*)(ob + 103563264);
  float*          Wt1  = (float*)(ob + 134217728);
  unsigned short* Wt2f = (unsigned short*)(ob + 134283264);
  float*          R2   = (float*)ws;
  unsigned short* C2b  = (unsigned short*)(ws + 51380224);
  unsigned short* Wt3f = (unsigned short*)(ws + 77070336);

  k0_prep  <<<dim3(272),     dim3(256), 0, stream>>>(w_conv1, w_conv2, w_conv3, Wt1, Wt2f, Wt3f);
  k1_tconv <<<dim3(25088),   dim3(256), 0, stream>>>(x, A, w1, w3, w5, w7);
  k2_conv1 <<<dim3(784),     dim3(256), 0, stream>>>(A, R2, R2b, Wt1, g1, b1);
  k3_conv21<<<dim3(784),     dim3(256), 0, stream>>>(R2, Yv, w_conv21, g21, b21);
  k4_corr  <<<dim3(64 * 14), dim3(256), 0, stream>>>(Yv, CO, g22, b22);
  k5_conv22<<<dim3(784),     dim3(256), 0, stream>>>(CO, R2, O2, w_conv22, g23, b23);
  k6_mfma  <<<dim3(64 * 14), dim3(256), 0, stream>>>(R2b, O2, C2b, Wt2f, g2, b2);
  k7_mfma  <<<dim3(64 * 49), dim3(256), 0, stream>>>(C2b, x, (float*)d_out, Wt3f, g3, b3);
}

// Round 13
// 492.961 us; speedup vs baseline: 5.0323x; 1.3730x over previous
//
#include <hip/hip_runtime.h>

// MsCorrBlock: B=8 T=8 C=256 PL=64 CR=16 H=W=56 HW=3136 NT=64 PS=7 KK=49
// Output dtype: FLOAT32 (205,520,896 B). BNI = 1/sqrt(1+1e-5).

#define MSC_BNI 0.9999950000374997f

typedef __attribute__((ext_vector_type(8))) short bf16x8;
typedef __attribute__((ext_vector_type(4))) float f32x4;

static __device__ __forceinline__ float b2f(unsigned short h) {
  return __uint_as_float(((unsigned int)h) << 16);
}
static __device__ __forceinline__ unsigned short f2b(float f) {
  unsigned int u = __float_as_uint(f);
  u = u + 0x7FFFu + ((u >> 16) & 1u);   // round to nearest even
  return (unsigned short)(u >> 16);
}

// K0: pack bf16 MFMA A-fragments.
//   Wt2f [tap9][kc2][m4][lane64][e8]: w2[o=m*16+(l&15)][c=kc*32+(l>>4)*8+e][tap]
//   Wt3f [kc2][m16][lane64][e8]:      w3[o=m*16+(l&15)][c=kc*32+(l>>4)*8+e]
//   Wt1f [kc8][m4][lane64][e8]:       w1[o=m*16+(l&15)][c=kc*32+(l>>4)*8+e]
__global__ __launch_bounds__(256) void k0_prep(
    const float* w1, const float* w2, const float* w3,
    unsigned short* Wt1f, unsigned short* Wt2f, unsigned short* Wt3f) {
  int idx = blockIdx.x * 256 + threadIdx.x;
  if (idx < 36864) {
    int j = idx;
    int e = j & 7;
    int lane = (j >> 3) & 63;
    int m = (j >> 9) & 3;
    int kc = (j >> 11) & 1;
    int tap = j >> 12;                       // 0..8
    int o = m * 16 + (lane & 15);
    int c = kc * 32 + (lane >> 4) * 8 + e;
    Wt2f[j] = f2b(w2[(o * 64 + c) * 9 + tap]);
  } else if (idx < 36864 + 16384) {
    int j = idx - 36864;
    int e = j & 7;
    int lane = (j >> 3) & 63;
    int m = (j >> 9) & 15;
    int kc = j >> 13;                        // 0..1
    int o = m * 16 + (lane & 15);
    int c = kc * 32 + (lane >> 4) * 8 + e;
    Wt3f[j] = f2b(w3[o * 64 + c]);
  } else if (idx < 36864 + 16384 + 16384) {
    int j = idx - 36864 - 16384;
    int e = j & 7;
    int lane = (j >> 3) & 63;
    int m = (j >> 9) & 3;
    int kc = j >> 11;                        // 0..7
    int o = m * 16 + (lane & 15);
    int c = kc * 32 + (lane >> 4) * 8 + e;
    Wt1f[j] = f2b(w1[o * 256 + c]);
  }
}

// K1: per-channel temporal conv (K=1/3/5/7 by channel quarter), x fp32 -> A bf16.
__global__ __launch_bounds__(256, 8) void k1_tconv(
    const float* x, unsigned short* A,
    const float* w1, const float* w3, const float* w5, const float* w7) {
  int i = blockIdx.x * 256 + threadIdx.x;       // over 8*256*3136 = 6,422,528
  if (i >= 6422528) return;
  int hw = i % 3136;
  int bc = i / 3136;
  int c = bc & 255;
  int b = bc >> 8;
  int q = c >> 6, cc = c & 63;
  float wf[7];
#pragma unroll
  for (int k = 0; k < 7; k++) wf[k] = 0.f;
  if (q == 0) { wf[3] = w1[cc]; }
  else if (q == 1) { wf[2] = w3[cc*3]; wf[3] = w3[cc*3+1]; wf[4] = w3[cc*3+2]; }
  else if (q == 2) { wf[1] = w5[cc*5]; wf[2] = w5[cc*5+1]; wf[3] = w5[cc*5+2]; wf[4] = w5[cc*5+3]; wf[5] = w5[cc*5+4]; }
  else { wf[0] = w7[cc*7]; wf[1] = w7[cc*7+1]; wf[2] = w7[cc*7+2]; wf[3] = w7[cc*7+3]; wf[4] = w7[cc*7+4]; wf[5] = w7[cc*7+5]; wf[6] = w7[cc*7+6]; }

  int base = (b * 8 * 256 + c) * 3136 + hw;     // t=0 element
  int tstr = 256 * 3136;
  float xv[8];
#pragma unroll
  for (int t = 0; t < 8; t++) xv[t] = x[base + t * tstr];
#pragma unroll
  for (int t = 0; t < 8; t++) {
    float a = 0.f;
#pragma unroll
    for (int d = -3; d <= 3; d++) {
      int ts = t + d;
      if (ts >= 0 && ts < 8) a = fmaf(wf[d + 3], xv[ts], a);
    }
    A[base + t * tstr] = f2b(a);
  }
}

// K2: 1x1 conv 256->64 via MFMA + BN + ReLU.  A bf16 -> R2b bf16.
// Block = (n, 64 cols). LDS sA[col64][c256] bf16 swizzled. Wave = 1 N-tile.
__global__ __launch_bounds__(256, 2) void k2_mfma(
    const unsigned short* A, unsigned short* R2b,
    const unsigned short* Wt1f, const float* g, const float* bb) {
  __shared__ unsigned short sA[16384];          // 32 KB
  int n = blockIdx.x / 49;
  int hw0 = (blockIdx.x % 49) * 64;
  const unsigned short* Ab = A + n * 256 * 3136 + hw0;
  for (int idx = threadIdx.x; idx < 16384; idx += 256) {
    int c = idx >> 6, col = idx & 63;
    sA[(col * 256 + c) ^ ((col & 7) << 3)] = Ab[c * 3136 + col];
  }
  __syncthreads();
  int l = threadIdx.x & 63;
  int wv = threadIdx.x >> 6;                    // N-tile
  int l15 = l & 15, l4 = l >> 4;
  f32x4 acc[4];
#pragma unroll
  for (int m = 0; m < 4; m++) acc[m] = (f32x4){0.f, 0.f, 0.f, 0.f};
#pragma unroll
  for (int kc = 0; kc < 8; kc++) {
    int colt = wv * 16 + l15;
    int us = (colt * 256 + kc * 32 + (l4 << 3)) ^ ((colt & 7) << 3);
    bf16x8 b = *(const bf16x8*)(sA + us);
#pragma unroll
    for (int m = 0; m < 4; m++) {
      bf16x8 a = *(const bf16x8*)(Wt1f + (((kc * 4 + m) * 64 + l) << 3));
      acc[m] = __builtin_amdgcn_mfma_f32_16x16x32_bf16(a, b, acc[m], 0, 0, 0);
    }
  }
  int col = hw0 + wv * 16 + l15;
#pragma unroll
  for (int m = 0; m < 4; m++) {
#pragma unroll
    for (int r = 0; r < 4; r++) {
      int o = m * 16 + l4 * 4 + r;
      float v = fmaxf(fmaf(acc[m][r], g[o] * MSC_BNI, bb[o]), 0.f);
      R2b[(n * 64 + o) * 3136 + col] = f2b(v);
    }
  }
}

// K3: 1x1 conv 64->16 + BN + ReLU.  R2b bf16 -> Y fp32.  Column in registers.
__global__ __launch_bounds__(256, 2) void k3_conv21(
    const unsigned short* R2b, float* Y,
    const float* w, const float* g, const float* bb) {
  int i = blockIdx.x * 256 + threadIdx.x;       // over 200,704
  int n = i / 3136;
  int hw = i - n * 3136;
  const unsigned short* Rb = R2b + n * 64 * 3136 + hw;
  float creg[64];
#pragma unroll
  for (int c = 0; c < 64; c++) creg[c] = b2f(Rb[c * 3136]);
  float* Yb = Y + n * 16 * 3136 + hw;
  for (int o = 0; o < 16; o++) {
    const float* wr = w + o * 64;               // uniform, contiguous
    float a0 = 0.f, a1 = 0.f, a2 = 0.f, a3 = 0.f;
#pragma unroll
    for (int c = 0; c < 16; c++) {
      a0 = fmaf(wr[4*c+0], creg[4*c+0], a0);
      a1 = fmaf(wr[4*c+1], creg[4*c+1], a1);
      a2 = fmaf(wr[4*c+2], creg[4*c+2], a2);
      a3 = fmaf(wr[4*c+3], creg[4*c+3], a3);
    }
    float acc = (a0 + a1) + (a2 + a3);
    Yb[o * 3136] = fmaxf(fmaf(acc, g[o] * MSC_BNI, bb[o]), 0.f);
  }
}

// K4: 7x7-displacement correlation (vs t+1 clamped frame) /16 + BN + ReLU.
__global__ __launch_bounds__(256) void k4_corr(
    const float* Y, float* CO, const float* g, const float* bb) {
  __shared__ float sb[10][16][62];              // rows h0-3..h0+6, ch, cols -3..58
  int n = blockIdx.x / 14;
  int h0 = (blockIdx.x % 14) * 4;
  int t = n & 7;
  int n2 = (t < 7) ? n + 1 : n;
  const float* Yb = Y + n2 * 16 * 3136;
  for (int idx = threadIdx.x; idx < 9920; idx += 256) {
    int r = idx / 992;
    int rem = idx - r * 992;
    int ch = rem / 62;
    int cl = rem - ch * 62;
    int gr = h0 - 3 + r, gc = cl - 3;
    float v = 0.f;
    if (gr >= 0 && gr < 56 && gc >= 0 && gc < 56)
      v = Yb[ch * 3136 + gr * 56 + gc];
    sb[r][ch][cl] = v;
  }
  __syncthreads();
  int pos = threadIdx.x;
  if (pos < 224) {
    int hl = pos / 56, wcol = pos - (pos / 56) * 56;
    float a[16];
    const float* Ya = Y + n * 16 * 3136 + (h0 + hl) * 56 + wcol;
#pragma unroll
    for (int c = 0; c < 16; c++) a[c] = Ya[c * 3136];
    float* Cp = CO + n * 49 * 3136 + (h0 + hl) * 56 + wcol;
    for (int di = 0; di < 7; di++) {
      for (int dj = 0; dj < 7; dj++) {
        float s = 0.f;
#pragma unroll
        for (int c = 0; c < 16; c++) s = fmaf(a[c], sb[hl + di][c][wcol + dj], s);
        int k = di * 7 + dj;
        float v = fmaf(s * 0.0625f, g[k] * MSC_BNI, bb[k]);
        Cp[k * 3136] = fmaxf(v, 0.f);
      }
    }
  }
}

// K5: 1x1 conv 49->64 + BN + R2b-add + ReLU -> O2 fp32. Column kernel.
__global__ __launch_bounds__(256, 2) void k5_conv22(
    const float* CO, const unsigned short* R2b, float* O2,
    const float* w, const float* g, const float* bb) {
  int i = blockIdx.x * 256 + threadIdx.x;       // over 200,704
  int n = i / 3136;
  int hw = i - n * 3136;
  float co[49];
  const float* pco = CO + n * 49 * 3136 + hw;
#pragma unroll
  for (int c = 0; c < 49; c++) co[c] = pco[c * 3136];
  const unsigned short* Rb = R2b + n * 64 * 3136 + hw;
  float* Ob = O2 + n * 64 * 3136 + hw;
  for (int o = 0; o < 64; o++) {
    const float* wr = w + o * 49;               // uniform, contiguous
    float s = 0.f;
#pragma unroll
    for (int c = 0; c < 49; c++) s = fmaf(wr[c], co[c], s);
    Ob[o * 3136] = fmaxf(fmaf(s, g[o] * MSC_BNI, bb[o]) + b2f(Rb[o * 3136]), 0.f);
  }
}

// K6: 3x3 conv 64->64 via MFMA implicit GEMM + BN + ReLU + O2 -> C2b bf16.
__global__ __launch_bounds__(256, 2) void k6_mfma(
    const unsigned short* R2b, const float* O2, unsigned short* C2b,
    const unsigned short* Wt2f, const float* g2, const float* b2) {
  __shared__ unsigned short sIn[22272];         // 6*58*64, 44,544 B
  int n = blockIdx.x / 14;
  int h0 = (blockIdx.x % 14) * 4;
  const unsigned short* Rb = R2b + n * 64 * 3136;
  for (int idx = threadIdx.x; idx < 22272; idx += 256) {
    int c = idx / 348;
    int rem = idx - c * 348;
    int row = rem / 58, col = rem - row * 58;
    int gr = h0 - 1 + row, gc = col - 1;
    unsigned short v = 0;
    if (gr >= 0 && gr < 56 && gc >= 0 && gc < 56)
      v = Rb[c * 3136 + gr * 56 + gc];
    sIn[(((row * 58 + col) * 64) + c) ^ ((col & 7) << 3)] = v;
  }
  __syncthreads();
  int l = threadIdx.x & 63;
  int wv = threadIdx.x >> 6;                    // 0..3
  int l15 = l & 15, l4 = l >> 4;
  f32x4 acc[4][4];
#pragma unroll
  for (int m = 0; m < 4; m++)
#pragma unroll
    for (int t = 0; t < 4; t++) acc[m][t] = (f32x4){0.f, 0.f, 0.f, 0.f};

  for (int tap = 0; tap < 9; tap++) {
    int ky = tap / 3;
    int kx = tap - ky * 3;
    for (int kc = 0; kc < 2; kc++) {
      bf16x8 a[4];
#pragma unroll
      for (int m = 0; m < 4; m++)
        a[m] = *(const bf16x8*)(Wt2f + ((((tap * 2 + kc) * 4 + m) * 64 + l) << 3));
#pragma unroll
      for (int t = 0; t < 4; t++) {
        int ct = wv * 4 + t;
        int rowt = ct >> 2, col0 = (ct & 3) << 4;
        int lcol = col0 + l15 + kx;
        if (lcol > 57) lcol = 57;               // discarded cols read padding
        int us = ((((rowt + ky) * 58 + lcol) * 64) + kc * 32 + (l4 << 3))
                 ^ ((lcol & 7) << 3);
        bf16x8 b = *(const bf16x8*)(sIn + us);
#pragma unroll
        for (int m = 0; m < 4; m++)
          acc[m][t] = __builtin_amdgcn_mfma_f32_16x16x32_bf16(a[m], b, acc[m][t], 0, 0, 0);
      }
    }
  }

#pragma unroll
  for (int t = 0; t < 4; t++) {
    int ct = wv * 4 + t;
    int rowt = ct >> 2, col0 = (ct & 3) << 4;
    int cc = col0 + l15;
    if (cc < 56) {
      int hw = (h0 + rowt) * 56 + cc;
      int base = n * 64 * 3136 + hw;
#pragma unroll
      for (int m = 0; m < 4; m++) {
#pragma unroll
        for (int r = 0; r < 4; r++) {
          int o = m * 16 + l4 * 4 + r;
          int off = base + o * 3136;
          float v = fmaxf(fmaf(acc[m][t][r], g2[o] * MSC_BNI, b2[o]), 0.f) + O2[off];
          C2b[off] = f2b(v);
        }
      }
    }
  }
}

// K7: 1x1 conv 64->256 via MFMA GEMM + BN + x-residual + ReLU -> d_out fp32.
// LDS-transposed epilogue: acc -> sOut[64][68] -> float4 coalesced stores.
__global__ __launch_bounds__(256, 2) void k7_mfma(
    const unsigned short* C2b, const float* x, float* outp,
    const unsigned short* Wt3f, const float* g, const float* bb) {
  __shared__ unsigned short sC[4096];           // 8 KB
  __shared__ float sOut[64 * 68];               // 17,408 B
  int n = blockIdx.x / 49;
  int hw0 = (blockIdx.x % 49) * 64;
  const unsigned short* Cb = C2b + n * 64 * 3136 + hw0;
  for (int idx = threadIdx.x; idx < 4096; idx += 256) {
    int c = idx >> 6, col = idx & 63;
    sC[(col * 64 + c) ^ ((col & 7) << 3)] = Cb[c * 3136 + col];
  }
  __syncthreads();
  int l = threadIdx.x & 63;
  int wv = threadIdx.x >> 6;                    // 0..3
  int l15 = l & 15, l4 = l >> 4;
  f32x4 acc[4][4];
#pragma unroll
  for (int m = 0; m < 4; m++)
#pragma unroll
    for (int t = 0; t < 4; t++) acc[m][t] = (f32x4){0.f, 0.f, 0.f, 0.f};

#pragma unroll
  for (int kc = 0; kc < 2; kc++) {
    bf16x8 a[4];
#pragma unroll
    for (int m = 0; m < 4; m++)
      a[m] = *(const bf16x8*)(Wt3f + (((kc * 16 + wv * 4 + m) * 64 + l) << 3));
#pragma unroll
    for (int t = 0; t < 4; t++) {
      int us = (((t * 16 + l15) * 64) + kc * 32 + (l4 << 3)) ^ ((l15 & 7) << 3);
      bf16x8 b = *(const bf16x8*)(sC + us);
#pragma unroll
      for (int m = 0; m < 4; m++)
        acc[m][t] = __builtin_amdgcn_mfma_f32_16x16x32_bf16(a[m], b, acc[m][t], 0, 0, 0);
    }
  }

  // epilogue: 4 passes; pass m covers o = wv*64 + m*16 + [0,16) for wv 0..3.
  for (int m = 0; m < 4; m++) {
#pragma unroll
    for (int t = 0; t < 4; t++)
#pragma unroll
      for (int r = 0; r < 4; r++)
        sOut[(wv * 16 + l4 * 4 + r) * 68 + t * 16 + l15] = acc[m][t][r];
    __syncthreads();
#pragma unroll
    for (int s = 0; s < 4; s++) {
      int ro = (threadIdx.x >> 4) + s * 16;     // 0..63
      int o = (ro >> 4) * 64 + m * 16 + (ro & 15);
      int colq = (threadIdx.x & 15) * 4;
      float4 v = *(float4*)&sOut[ro * 68 + colq];
      int off = (n * 256 + o) * 3136 + hw0 + colq;
      float4 xv = *(const float4*)(x + off);
      float sg = g[o] * MSC_BNI, bo = bb[o];
      float4 ov;
      ov.x = fmaxf(fmaf(v.x, sg, bo) + xv.x, 0.f);
      ov.y = fmaxf(fmaf(v.y, sg, bo) + xv.y, 0.f);
      ov.z = fmaxf(fmaf(v.z, sg, bo) + xv.z, 0.f);
      ov.w = fmaxf(fmaf(v.w, sg, bo) + xv.w, 0.f);
      *(float4*)(outp + off) = ov;
    }
    __syncthreads();
  }
}

extern "C" void kernel_launch(void* const* d_in, const int* in_sizes, int n_in,
                              void* d_out, int out_size, void* d_ws, size_t ws_size,
                              hipStream_t stream) {
  const float* x        = (const float*)d_in[0];
  const float* w1       = (const float*)d_in[1];
  const float* w3       = (const float*)d_in[2];
  const float* w5       = (const float*)d_in[3];
  const float* w7       = (const float*)d_in[4];
  const float* w_conv1  = (const float*)d_in[5];
  const float* g1       = (const float*)d_in[6];
  const float* b1       = (const float*)d_in[7];
  const float* w_conv21 = (const float*)d_in[8];
  const float* g21      = (const float*)d_in[9];
  const float* b21      = (const float*)d_in[10];
  const float* g22      = (const float*)d_in[11];
  const float* b22      = (const float*)d_in[12];
  const float* w_conv22 = (const float*)d_in[13];
  const float* g23      = (const float*)d_in[14];
  const float* b23      = (const float*)d_in[15];
  const float* w_conv2  = (const float*)d_in[16];
  const float* g2       = (const float*)d_in[17];
  const float* b2       = (const float*)d_in[18];
  const float* w_conv3  = (const float*)d_in[19];
  const float* g3       = (const float*)d_in[20];
  const float* b3       = (const float*)d_in[21];

  // d_out (fp32, 205,520,896 B) scratch map (all dead before K7's rewrite):
  //   A    bf16 [0 .. 102,760,448)            K1 w, K2 r
  //   Y    fp32 [0 .. 12,845,056)             K3 w, K4 r   (A dead)
  //   CO   fp32 [12,845,056 .. 52,183,040)    K4 w, K5 r
  //   O2   fp32 [52,183,040 .. 103,563,264)   K5 w, K6 r
  //   R2b  bf16 [103,563,264 .. 129,253,376)  K2 w; K3,K5,K6 r
  //   Wt2f bf16 [134,217,728 .. +73,728)      K0 w, K6 r
  //   Wt1f bf16 [134,291,456 .. +32,768)      K0 w, K2 r
  // d_ws:
  //   C2b  bf16 [0 .. 25,690,112)             K6 w, K7 r
  //   Wt3f bf16 [25,690,112 .. +32,768)       K0 w, K7 r (K7 overwrites d_out)
  char* ob = (char*)d_out;
  char* ws = (char*)d_ws;
  unsigned short* A    = (unsigned short*)ob;
  float*          Yv   = (float*)ob;
  float*          CO   = (float*)(ob + 12845056);
  float*          O2   = (float*)(ob + 52183040);
  unsigned short* R2b  = (unsigned short*)(ob + 103563264);
  unsigned short* Wt2f = (unsigned short*)(ob + 134217728);
  unsigned short* Wt1f = (unsigned short*)(ob + 134291456);
  unsigned short* C2b  = (unsigned short*)ws;
  unsigned short* Wt3f = (unsigned short*)(ws + 25690112);

  k0_prep  <<<dim3(272),     dim3(256), 0, stream>>>(w_conv1, w_conv2, w_conv3, Wt1f, Wt2f, Wt3f);
  k1_tconv <<<dim3(25088),   dim3(256), 0, stream>>>(x, A, w1, w3, w5, w7);
  k2_mfma  <<<dim3(64 * 49), dim3(256), 0, stream>>>(A, R2b, Wt1f, g1, b1);
  k3_conv21<<<dim3(784),     dim3(256), 0, stream>>>(R2b, Yv, w_conv21, g21, b21);
  k4_corr  <<<dim3(64 * 14), dim3(256), 0, stream>>>(Yv, CO, g22, b22);
  k5_conv22<<<dim3(784),     dim3(256), 0, stream>>>(CO, R2b, O2, w_conv22, g23, b23);
  k6_mfma  <<<dim3(64 * 14), dim3(256), 0, stream>>>(R2b, O2, C2b, Wt2f, g2, b2);
  k7_mfma  <<<dim3(64 * 49), dim3(256), 0, stream>>>(C2b, x, (float*)d_out, Wt3f, g3, b3);
}

// Round 14
// 415.747 us; speedup vs baseline: 5.9670x; 1.1857x over previous
//
#include <hip/hip_runtime.h>

// MsCorrBlock: B=8 T=8 C=256 PL=64 CR=16 H=W=56 HW=3136 NT=64 PS=7 KK=49
// Output dtype: FLOAT32 (205,520,896 B). BNI = 1/sqrt(1+1e-5).

#define MSC_BNI 0.9999950000374997f

typedef __attribute__((ext_vector_type(8))) short bf16x8;
typedef __attribute__((ext_vector_type(4))) float f32x4;

static __device__ __forceinline__ float b2f(unsigned short h) {
  return __uint_as_float(((unsigned int)h) << 16);
}
static __device__ __forceinline__ unsigned short f2b(float f) {
  unsigned int u = __float_as_uint(f);
  u = u + 0x7FFFu + ((u >> 16) & 1u);   // round to nearest even
  return (unsigned short)(u >> 16);
}

// K0: pack bf16 MFMA A-fragments.
//   Wt2f [tap9][kc2][m4][lane64][e8]: w2[o=m*16+(l&15)][c=kc*32+(l>>4)*8+e][tap]
//   Wt3f [kc2][m16][lane64][e8]:      w3[o][c]
//   Wt1f [kc8][m4][lane64][e8]:       w1[o][c]
//   Wt4f [kc2][m4][lane64][e8]:       w22[o][c] (c>=49 -> 0)
__global__ __launch_bounds__(256) void k0_prep(
    const float* w1, const float* w2, const float* w3, const float* w22,
    unsigned short* Wt1f, unsigned short* Wt2f, unsigned short* Wt3f,
    unsigned short* Wt4f) {
  int idx = blockIdx.x * 256 + threadIdx.x;
  if (idx < 36864) {
    int j = idx;
    int e = j & 7;
    int lane = (j >> 3) & 63;
    int m = (j >> 9) & 3;
    int kc = (j >> 11) & 1;
    int tap = j >> 12;                       // 0..8
    int o = m * 16 + (lane & 15);
    int c = kc * 32 + (lane >> 4) * 8 + e;
    Wt2f[j] = f2b(w2[(o * 64 + c) * 9 + tap]);
  } else if (idx < 36864 + 16384) {
    int j = idx - 36864;
    int e = j & 7;
    int lane = (j >> 3) & 63;
    int m = (j >> 9) & 15;
    int kc = j >> 13;                        // 0..1
    int o = m * 16 + (lane & 15);
    int c = kc * 32 + (lane >> 4) * 8 + e;
    Wt3f[j] = f2b(w3[o * 64 + c]);
  } else if (idx < 36864 + 16384 + 16384) {
    int j = idx - 36864 - 16384;
    int e = j & 7;
    int lane = (j >> 3) & 63;
    int m = (j >> 9) & 3;
    int kc = j >> 11;                        // 0..7
    int o = m * 16 + (lane & 15);
    int c = kc * 32 + (lane >> 4) * 8 + e;
    Wt1f[j] = f2b(w1[o * 256 + c]);
  } else if (idx < 36864 + 16384 + 16384 + 4096) {
    int j = idx - 36864 - 16384 - 16384;
    int e = j & 7;
    int lane = (j >> 3) & 63;
    int m = (j >> 9) & 3;
    int kc = j >> 11;                        // 0..1
    int o = m * 16 + (lane & 15);
    int c = kc * 32 + (lane >> 4) * 8 + e;
    Wt4f[j] = (c < 49) ? f2b(w22[o * 49 + c]) : (unsigned short)0;
  }
}

// K1: per-channel temporal conv (K=1/3/5/7 by channel quarter), x fp32 -> A bf16.
__global__ __launch_bounds__(256, 8) void k1_tconv(
    const float* x, unsigned short* A,
    const float* w1, const float* w3, const float* w5, const float* w7) {
  int i = blockIdx.x * 256 + threadIdx.x;       // over 8*256*3136 = 6,422,528
  if (i >= 6422528) return;
  int hw = i % 3136;
  int bc = i / 3136;
  int c = bc & 255;
  int b = bc >> 8;
  int q = c >> 6, cc = c & 63;
  float wf[7];
#pragma unroll
  for (int k = 0; k < 7; k++) wf[k] = 0.f;
  if (q == 0) { wf[3] = w1[cc]; }
  else if (q == 1) { wf[2] = w3[cc*3]; wf[3] = w3[cc*3+1]; wf[4] = w3[cc*3+2]; }
  else if (q == 2) { wf[1] = w5[cc*5]; wf[2] = w5[cc*5+1]; wf[3] = w5[cc*5+2]; wf[4] = w5[cc*5+3]; wf[5] = w5[cc*5+4]; }
  else { wf[0] = w7[cc*7]; wf[1] = w7[cc*7+1]; wf[2] = w7[cc*7+2]; wf[3] = w7[cc*7+3]; wf[4] = w7[cc*7+4]; wf[5] = w7[cc*7+5]; wf[6] = w7[cc*7+6]; }

  int base = (b * 8 * 256 + c) * 3136 + hw;     // t=0 element
  int tstr = 256 * 3136;
  float xv[8];
#pragma unroll
  for (int t = 0; t < 8; t++) xv[t] = x[base + t * tstr];
#pragma unroll
  for (int t = 0; t < 8; t++) {
    float a = 0.f;
#pragma unroll
    for (int d = -3; d <= 3; d++) {
      int ts = t + d;
      if (ts >= 0 && ts < 8) a = fmaf(wf[d + 3], xv[ts], a);
    }
    A[base + t * tstr] = f2b(a);
  }
}

// K2: 1x1 conv 256->64 via MFMA + BN + ReLU.  A bf16 -> R2b bf16.
__global__ __launch_bounds__(256, 2) void k2_mfma(
    const unsigned short* A, unsigned short* R2b,
    const unsigned short* Wt1f, const float* g, const float* bb) {
  __shared__ unsigned short sA[16384];          // 32 KB
  int n = blockIdx.x / 49;
  int hw0 = (blockIdx.x % 49) * 64;
  const unsigned short* Ab = A + n * 256 * 3136 + hw0;
  for (int idx = threadIdx.x; idx < 16384; idx += 256) {
    int c = idx >> 6, col = idx & 63;
    sA[(col * 256 + c) ^ ((col & 7) << 3)] = Ab[c * 3136 + col];
  }
  __syncthreads();
  int l = threadIdx.x & 63;
  int wv = threadIdx.x >> 6;                    // N-tile
  int l15 = l & 15, l4 = l >> 4;
  f32x4 acc[4];
#pragma unroll
  for (int m = 0; m < 4; m++) acc[m] = (f32x4){0.f, 0.f, 0.f, 0.f};
#pragma unroll
  for (int kc = 0; kc < 8; kc++) {
    int colt = wv * 16 + l15;
    int us = (colt * 256 + kc * 32 + (l4 << 3)) ^ ((colt & 7) << 3);
    bf16x8 b = *(const bf16x8*)(sA + us);
#pragma unroll
    for (int m = 0; m < 4; m++) {
      bf16x8 a = *(const bf16x8*)(Wt1f + (((kc * 4 + m) * 64 + l) << 3));
      acc[m] = __builtin_amdgcn_mfma_f32_16x16x32_bf16(a, b, acc[m], 0, 0, 0);
    }
  }
  int col = hw0 + wv * 16 + l15;
#pragma unroll
  for (int m = 0; m < 4; m++) {
#pragma unroll
    for (int r = 0; r < 4; r++) {
      int o = m * 16 + l4 * 4 + r;
      float v = fmaxf(fmaf(acc[m][r], g[o] * MSC_BNI, bb[o]), 0.f);
      R2b[(n * 64 + o) * 3136 + col] = f2b(v);
    }
  }
}

// K3: 1x1 conv 64->16 + BN + ReLU.  R2b bf16 -> Y fp32.  Column in registers.
__global__ __launch_bounds__(256, 2) void k3_conv21(
    const unsigned short* R2b, float* Y,
    const float* w, const float* g, const float* bb) {
  int i = blockIdx.x * 256 + threadIdx.x;       // over 200,704
  int n = i / 3136;
  int hw = i - n * 3136;
  const unsigned short* Rb = R2b + n * 64 * 3136 + hw;
  float creg[64];
#pragma unroll
  for (int c = 0; c < 64; c++) creg[c] = b2f(Rb[c * 3136]);
  float* Yb = Y + n * 16 * 3136 + hw;
  for (int o = 0; o < 16; o++) {
    const float* wr = w + o * 64;               // uniform, contiguous
    float a0 = 0.f, a1 = 0.f, a2 = 0.f, a3 = 0.f;
#pragma unroll
    for (int c = 0; c < 16; c++) {
      a0 = fmaf(wr[4*c+0], creg[4*c+0], a0);
      a1 = fmaf(wr[4*c+1], creg[4*c+1], a1);
      a2 = fmaf(wr[4*c+2], creg[4*c+2], a2);
      a3 = fmaf(wr[4*c+3], creg[4*c+3], a3);
    }
    float acc = (a0 + a1) + (a2 + a3);
    Yb[o * 3136] = fmaxf(fmaf(acc, g[o] * MSC_BNI, bb[o]), 0.f);
  }
}

// K4: 7x7-displacement correlation /16 + BN + ReLU -> CO bf16.
__global__ __launch_bounds__(256) void k4_corr(
    const float* Y, unsigned short* CO, const float* g, const float* bb) {
  __shared__ float sb[10][16][62];              // rows h0-3..h0+6, ch, cols -3..58
  int n = blockIdx.x / 14;
  int h0 = (blockIdx.x % 14) * 4;
  int t = n & 7;
  int n2 = (t < 7) ? n + 1 : n;
  const float* Yb = Y + n2 * 16 * 3136;
  for (int idx = threadIdx.x; idx < 9920; idx += 256) {
    int r = idx / 992;
    int rem = idx - r * 992;
    int ch = rem / 62;
    int cl = rem - ch * 62;
    int gr = h0 - 3 + r, gc = cl - 3;
    float v = 0.f;
    if (gr >= 0 && gr < 56 && gc >= 0 && gc < 56)
      v = Yb[ch * 3136 + gr * 56 + gc];
    sb[r][ch][cl] = v;
  }
  __syncthreads();
  int pos = threadIdx.x;
  if (pos < 224) {
    int hl = pos / 56, wcol = pos - (pos / 56) * 56;
    float a[16];
    const float* Ya = Y + n * 16 * 3136 + (h0 + hl) * 56 + wcol;
#pragma unroll
    for (int c = 0; c < 16; c++) a[c] = Ya[c * 3136];
    unsigned short* Cp = CO + n * 49 * 3136 + (h0 + hl) * 56 + wcol;
    for (int di = 0; di < 7; di++) {
      for (int dj = 0; dj < 7; dj++) {
        float s = 0.f;
#pragma unroll
        for (int c = 0; c < 16; c++) s = fmaf(a[c], sb[hl + di][c][wcol + dj], s);
        int k = di * 7 + dj;
        float v = fmaf(s * 0.0625f, g[k] * MSC_BNI, bb[k]);
        Cp[k * 3136] = f2b(fmaxf(v, 0.f));
      }
    }
  }
}

// K5: 1x1 conv 49->64 via MFMA (K padded to 64) + BN + R2b-add + ReLU -> O2b bf16.
__global__ __launch_bounds__(256, 2) void k5_mfma(
    const unsigned short* COb, const unsigned short* R2b, unsigned short* O2b,
    const unsigned short* Wt4f, const float* g, const float* bb) {
  __shared__ unsigned short sCO[4096];          // 8 KB
  int n = blockIdx.x / 49;
  int hw0 = (blockIdx.x % 49) * 64;
  const unsigned short* Cb = COb + n * 49 * 3136 + hw0;
  for (int idx = threadIdx.x; idx < 4096; idx += 256) {
    int c = idx >> 6, col = idx & 63;
    unsigned short v = (c < 49) ? Cb[c * 3136 + col] : (unsigned short)0;
    sCO[(col * 64 + c) ^ ((col & 7) << 3)] = v;
  }
  __syncthreads();
  int l = threadIdx.x & 63;
  int wv = threadIdx.x >> 6;                    // N-tile
  int l15 = l & 15, l4 = l >> 4;
  f32x4 acc[4];
#pragma unroll
  for (int m = 0; m < 4; m++) acc[m] = (f32x4){0.f, 0.f, 0.f, 0.f};
#pragma unroll
  for (int kc = 0; kc < 2; kc++) {
    int colt = wv * 16 + l15;
    int us = (colt * 64 + kc * 32 + (l4 << 3)) ^ ((colt & 7) << 3);
    bf16x8 b = *(const bf16x8*)(sCO + us);
#pragma unroll
    for (int m = 0; m < 4; m++) {
      bf16x8 a = *(const bf16x8*)(Wt4f + (((kc * 4 + m) * 64 + l) << 3));
      acc[m] = __builtin_amdgcn_mfma_f32_16x16x32_bf16(a, b, acc[m], 0, 0, 0);
    }
  }
  int col = hw0 + wv * 16 + l15;
#pragma unroll
  for (int m = 0; m < 4; m++) {
#pragma unroll
    for (int r = 0; r < 4; r++) {
      int o = m * 16 + l4 * 4 + r;
      int off = (n * 64 + o) * 3136 + col;
      float v = fmaxf(fmaf(acc[m][r], g[o] * MSC_BNI, bb[o]) + b2f(R2b[off]), 0.f);
      O2b[off] = f2b(v);
    }
  }
}

// K6: 3x3 conv 64->64 via MFMA implicit GEMM + BN + ReLU + O2b -> C2b bf16.
__global__ __launch_bounds__(256, 2) void k6_mfma(
    const unsigned short* R2b, const unsigned short* O2b, unsigned short* C2b,
    const unsigned short* Wt2f, const float* g2, const float* b2) {
  __shared__ unsigned short sIn[22272];         // 6*58*64, 44,544 B
  int n = blockIdx.x / 14;
  int h0 = (blockIdx.x % 14) * 4;
  const unsigned short* Rb = R2b + n * 64 * 3136;
  for (int idx = threadIdx.x; idx < 22272; idx += 256) {
    int c = idx / 348;
    int rem = idx - c * 348;
    int row = rem / 58, col = rem - row * 58;
    int gr = h0 - 1 + row, gc = col - 1;
    unsigned short v = 0;
    if (gr >= 0 && gr < 56 && gc >= 0 && gc < 56)
      v = Rb[c * 3136 + gr * 56 + gc];
    sIn[(((row * 58 + col) * 64) + c) ^ ((col & 7) << 3)] = v;
  }
  __syncthreads();
  int l = threadIdx.x & 63;
  int wv = threadIdx.x >> 6;                    // 0..3
  int l15 = l & 15, l4 = l >> 4;
  f32x4 acc[4][4];
#pragma unroll
  for (int m = 0; m < 4; m++)
#pragma unroll
    for (int t = 0; t < 4; t++) acc[m][t] = (f32x4){0.f, 0.f, 0.f, 0.f};

  for (int tap = 0; tap < 9; tap++) {
    int ky = tap / 3;
    int kx = tap - ky * 3;
    for (int kc = 0; kc < 2; kc++) {
      bf16x8 a[4];
#pragma unroll
      for (int m = 0; m < 4; m++)
        a[m] = *(const bf16x8*)(Wt2f + ((((tap * 2 + kc) * 4 + m) * 64 + l) << 3));
#pragma unroll
      for (int t = 0; t < 4; t++) {
        int ct = wv * 4 + t;
        int rowt = ct >> 2, col0 = (ct & 3) << 4;
        int lcol = col0 + l15 + kx;
        if (lcol > 57) lcol = 57;               // discarded cols read padding
        int us = ((((rowt + ky) * 58 + lcol) * 64) + kc * 32 + (l4 << 3))
                 ^ ((lcol & 7) << 3);
        bf16x8 b = *(const bf16x8*)(sIn + us);
#pragma unroll
        for (int m = 0; m < 4; m++)
          acc[m][t] = __builtin_amdgcn_mfma_f32_16x16x32_bf16(a[m], b, acc[m][t], 0, 0, 0);
      }
    }
  }

#pragma unroll
  for (int t = 0; t < 4; t++) {
    int ct = wv * 4 + t;
    int rowt = ct >> 2, col0 = (ct & 3) << 4;
    int cc = col0 + l15;
    if (cc < 56) {
      int hw = (h0 + rowt) * 56 + cc;
      int base = n * 64 * 3136 + hw;
#pragma unroll
      for (int m = 0; m < 4; m++) {
#pragma unroll
        for (int r = 0; r < 4; r++) {
          int o = m * 16 + l4 * 4 + r;
          int off = base + o * 3136;
          float v = fmaxf(fmaf(acc[m][t][r], g2[o] * MSC_BNI, b2[o]), 0.f)
                    + b2f(O2b[off]);
          C2b[off] = f2b(v);
        }
      }
    }
  }
}

// K7: 1x1 conv 64->256 via MFMA GEMM + BN + x-residual + ReLU -> d_out fp32.
// LDS-transposed epilogue: acc -> sOut[64][68] -> float4 coalesced stores.
__global__ __launch_bounds__(256, 2) void k7_mfma(
    const unsigned short* C2b, const float* x, float* outp,
    const unsigned short* Wt3f, const float* g, const float* bb) {
  __shared__ unsigned short sC[4096];           // 8 KB
  __shared__ float sOut[64 * 68];               // 17,408 B
  int n = blockIdx.x / 49;
  int hw0 = (blockIdx.x % 49) * 64;
  const unsigned short* Cb = C2b + n * 64 * 3136 + hw0;
  for (int idx = threadIdx.x; idx < 4096; idx += 256) {
    int c = idx >> 6, col = idx & 63;
    sC[(col * 64 + c) ^ ((col & 7) << 3)] = Cb[c * 3136 + col];
  }
  __syncthreads();
  int l = threadIdx.x & 63;
  int wv = threadIdx.x >> 6;                    // 0..3
  int l15 = l & 15, l4 = l >> 4;
  f32x4 acc[4][4];
#pragma unroll
  for (int m = 0; m < 4; m++)
#pragma unroll
    for (int t = 0; t < 4; t++) acc[m][t] = (f32x4){0.f, 0.f, 0.f, 0.f};

#pragma unroll
  for (int kc = 0; kc < 2; kc++) {
    bf16x8 a[4];
#pragma unroll
    for (int m = 0; m < 4; m++)
      a[m] = *(const bf16x8*)(Wt3f + (((kc * 16 + wv * 4 + m) * 64 + l) << 3));
#pragma unroll
    for (int t = 0; t < 4; t++) {
      int us = (((t * 16 + l15) * 64) + kc * 32 + (l4 << 3)) ^ ((l15 & 7) << 3);
      bf16x8 b = *(const bf16x8*)(sC + us);
#pragma unroll
      for (int m = 0; m < 4; m++)
        acc[m][t] = __builtin_amdgcn_mfma_f32_16x16x32_bf16(a[m], b, acc[m][t], 0, 0, 0);
    }
  }

  // epilogue: 4 passes; pass m covers o = wv*64 + m*16 + [0,16) for wv 0..3.
  for (int m = 0; m < 4; m++) {
#pragma unroll
    for (int t = 0; t < 4; t++)
#pragma unroll
      for (int r = 0; r < 4; r++)
        sOut[(wv * 16 + l4 * 4 + r) * 68 + t * 16 + l15] = acc[m][t][r];
    __syncthreads();
#pragma unroll
    for (int s = 0; s < 4; s++) {
      int ro = (threadIdx.x >> 4) + s * 16;     // 0..63
      int o = (ro >> 4) * 64 + m * 16 + (ro & 15);
      int colq = (threadIdx.x & 15) * 4;
      float4 v = *(float4*)&sOut[ro * 68 + colq];
      int off = (n * 256 + o) * 3136 + hw0 + colq;
      float4 xv = *(const float4*)(x + off);
      float sg = g[o] * MSC_BNI, bo = bb[o];
      float4 ov;
      ov.x = fmaxf(fmaf(v.x, sg, bo) + xv.x, 0.f);
      ov.y = fmaxf(fmaf(v.y, sg, bo) + xv.y, 0.f);
      ov.z = fmaxf(fmaf(v.z, sg, bo) + xv.z, 0.f);
      ov.w = fmaxf(fmaf(v.w, sg, bo) + xv.w, 0.f);
      *(float4*)(outp + off) = ov;
    }
    __syncthreads();
  }
}

extern "C" void kernel_launch(void* const* d_in, const int* in_sizes, int n_in,
                              void* d_out, int out_size, void* d_ws, size_t ws_size,
                              hipStream_t stream) {
  const float* x        = (const float*)d_in[0];
  const float* w1       = (const float*)d_in[1];
  const float* w3       = (const float*)d_in[2];
  const float* w5       = (const float*)d_in[3];
  const float* w7       = (const float*)d_in[4];
  const float* w_conv1  = (const float*)d_in[5];
  const float* g1       = (const float*)d_in[6];
  const float* b1       = (const float*)d_in[7];
  const float* w_conv21 = (const float*)d_in[8];
  const float* g21      = (const float*)d_in[9];
  const float* b21      = (const float*)d_in[10];
  const float* g22      = (const float*)d_in[11];
  const float* b22      = (const float*)d_in[12];
  const float* w_conv22 = (const float*)d_in[13];
  const float* g23      = (const float*)d_in[14];
  const float* b23      = (const float*)d_in[15];
  const float* w_conv2  = (const float*)d_in[16];
  const float* g2       = (const float*)d_in[17];
  const float* b2       = (const float*)d_in[18];
  const float* w_conv3  = (const float*)d_in[19];
  const float* g3       = (const float*)d_in[20];
  const float* b3       = (const float*)d_in[21];

  // d_out (fp32, 205,520,896 B) scratch map (all dead before K7's rewrite):
  //   A    bf16 [0 .. 102,760,448)            K1 w, K2 r
  //   Y    fp32 [0 .. 12,845,056)             K3 w, K4 r   (A dead)
  //   CO   bf16 [12,845,056 .. 32,513,152)    K4 w, K5 r
  //   O2b  bf16 [52,183,040 .. 77,873,152)    K5 w, K6 r
  //   R2b  bf16 [103,563,264 .. 129,253,376)  K2 w; K3,K5,K6 r
  //   Wt2f bf16 [134,217,728 .. +73,728)      K0 w, K6 r
  //   Wt1f bf16 [134,291,456 .. +32,768)      K0 w, K2 r
  //   Wt4f bf16 [134,324,224 .. +8,192)       K0 w, K5 r
  // d_ws:
  //   C2b  bf16 [0 .. 25,690,112)             K6 w, K7 r
  //   Wt3f bf16 [25,690,112 .. +32,768)       K0 w, K7 r (K7 overwrites d_out)
  char* ob = (char*)d_out;
  char* ws = (char*)d_ws;
  unsigned short* A    = (unsigned short*)ob;
  float*          Yv   = (float*)ob;
  unsigned short* CO   = (unsigned short*)(ob + 12845056);
  unsigned short* O2b  = (unsigned short*)(ob + 52183040);
  unsigned short* R2b  = (unsigned short*)(ob + 103563264);
  unsigned short* Wt2f = (unsigned short*)(ob + 134217728);
  unsigned short* Wt1f = (unsigned short*)(ob + 134291456);
  unsigned short* Wt4f = (unsigned short*)(ob + 134324224);
  unsigned short* C2b  = (unsigned short*)ws;
  unsigned short* Wt3f = (unsigned short*)(ws + 25690112);

  k0_prep  <<<dim3(288),     dim3(256), 0, stream>>>(w_conv1, w_conv2, w_conv3, w_conv22,
                                                     Wt1f, Wt2f, Wt3f, Wt4f);
  k1_tconv <<<dim3(25088),   dim3(256), 0, stream>>>(x, A, w1, w3, w5, w7);
  k2_mfma  <<<dim3(64 * 49), dim3(256), 0, stream>>>(A, R2b, Wt1f, g1, b1);
  k3_conv21<<<dim3(784),     dim3(256), 0, stream>>>(R2b, Yv, w_conv21, g21, b21);
  k4_corr  <<<dim3(64 * 14), dim3(256), 0, stream>>>(Yv, CO, g22, b22);
  k5_mfma  <<<dim3(64 * 49), dim3(256), 0, stream>>>(CO, R2b, O2b, Wt4f, g23, b23);
  k6_mfma  <<<dim3(64 * 14), dim3(256), 0, stream>>>(R2b, O2b, C2b, Wt2f, g2, b2);
  k7_mfma  <<<dim3(64 * 49), dim3(256), 0, stream>>>(C2b, x, (float*)d_out, Wt3f, g3, b3);
}

// Round 15
// 318.073 us; speedup vs baseline: 7.7993x; 1.3071x over previous
//
#include <hip/hip_runtime.h>

// MsCorrBlock: B=8 T=8 C=256 PL=64 CR=16 H=W=56 HW=3136 NT=64 PS=7 KK=49
// Output dtype: FLOAT32 (205,520,896 B). BNI = 1/sqrt(1+1e-5).

#define MSC_BNI 0.9999950000374997f

typedef __attribute__((ext_vector_type(8))) short bf16x8;
typedef __attribute__((ext_vector_type(4))) float f32x4;
struct __align__(8) ush4 { unsigned short v[4]; };

static __device__ __forceinline__ float b2f(unsigned short h) {
  return __uint_as_float(((unsigned int)h) << 16);
}
static __device__ __forceinline__ unsigned short f2b(float f) {
  unsigned int u = __float_as_uint(f);
  u = u + 0x7FFFu + ((u >> 16) & 1u);   // round to nearest even
  return (unsigned short)(u >> 16);
}

// K0: pack bf16 MFMA A-fragments (convention validated in k6/k7/k2/k5):
//   Wt2f [tap9][kc2][m4][lane64][e8]: w2[o=m*16+(l&15)][c=kc*32+(l>>4)*8+e][tap]
//   Wt3f [kc2][m16][lane64][e8]:      w3[o][c]
//   Wt1f [kc8][m4][lane64][e8]:       w1[o][c]
//   Wt4f [kc2][m4][lane64][e8]:       w22[o][c] (c>=49 -> 0)
__global__ __launch_bounds__(256) void k0_prep(
    const float* w1, const float* w2, const float* w3, const float* w22,
    unsigned short* Wt1f, unsigned short* Wt2f, unsigned short* Wt3f,
    unsigned short* Wt4f) {
  int idx = blockIdx.x * 256 + threadIdx.x;
  if (idx < 36864) {
    int j = idx;
    int e = j & 7;
    int lane = (j >> 3) & 63;
    int m = (j >> 9) & 3;
    int kc = (j >> 11) & 1;
    int tap = j >> 12;                       // 0..8
    int o = m * 16 + (lane & 15);
    int c = kc * 32 + (lane >> 4) * 8 + e;
    Wt2f[j] = f2b(w2[(o * 64 + c) * 9 + tap]);
  } else if (idx < 36864 + 16384) {
    int j = idx - 36864;
    int e = j & 7;
    int lane = (j >> 3) & 63;
    int m = (j >> 9) & 15;
    int kc = j >> 13;                        // 0..1
    int o = m * 16 + (lane & 15);
    int c = kc * 32 + (lane >> 4) * 8 + e;
    Wt3f[j] = f2b(w3[o * 64 + c]);
  } else if (idx < 36864 + 16384 + 16384) {
    int j = idx - 36864 - 16384;
    int e = j & 7;
    int lane = (j >> 3) & 63;
    int m = (j >> 9) & 3;
    int kc = j >> 11;                        // 0..7
    int o = m * 16 + (lane & 15);
    int c = kc * 32 + (lane >> 4) * 8 + e;
    Wt1f[j] = f2b(w1[o * 256 + c]);
  } else if (idx < 36864 + 16384 + 16384 + 4096) {
    int j = idx - 36864 - 16384 - 16384;
    int e = j & 7;
    int lane = (j >> 3) & 63;
    int m = (j >> 9) & 3;
    int kc = j >> 11;                        // 0..1
    int o = m * 16 + (lane & 15);
    int c = kc * 32 + (lane >> 4) * 8 + e;
    Wt4f[j] = (c < 49) ? f2b(w22[o * 49 + c]) : (unsigned short)0;
  }
}

// K1: per-channel temporal conv (K=1/3/5/7 by channel quarter), x fp32 -> A bf16.
__global__ __launch_bounds__(256, 8) void k1_tconv(
    const float* x, unsigned short* A,
    const float* w1, const float* w3, const float* w5, const float* w7) {
  int i = blockIdx.x * 256 + threadIdx.x;       // over 8*256*3136 = 6,422,528
  if (i >= 6422528) return;
  int hw = i % 3136;
  int bc = i / 3136;
  int c = bc & 255;
  int b = bc >> 8;
  int q = c >> 6, cc = c & 63;
  float wf[7];
#pragma unroll
  for (int k = 0; k < 7; k++) wf[k] = 0.f;
  if (q == 0) { wf[3] = w1[cc]; }
  else if (q == 1) { wf[2] = w3[cc*3]; wf[3] = w3[cc*3+1]; wf[4] = w3[cc*3+2]; }
  else if (q == 2) { wf[1] = w5[cc*5]; wf[2] = w5[cc*5+1]; wf[3] = w5[cc*5+2]; wf[4] = w5[cc*5+3]; wf[5] = w5[cc*5+4]; }
  else { wf[0] = w7[cc*7]; wf[1] = w7[cc*7+1]; wf[2] = w7[cc*7+2]; wf[3] = w7[cc*7+3]; wf[4] = w7[cc*7+4]; wf[5] = w7[cc*7+5]; wf[6] = w7[cc*7+6]; }

  int base = (b * 8 * 256 + c) * 3136 + hw;     // t=0 element
  int tstr = 256 * 3136;
  float xv[8];
#pragma unroll
  for (int t = 0; t < 8; t++) xv[t] = x[base + t * tstr];
#pragma unroll
  for (int t = 0; t < 8; t++) {
    float a = 0.f;
#pragma unroll
    for (int d = -3; d <= 3; d++) {
      int ts = t + d;
      if (ts >= 0 && ts < 8) a = fmaf(wf[d + 3], xv[ts], a);
    }
    A[base + t * tstr] = f2b(a);
  }
}

// K2: 1x1 conv 256->64 via MFMA + BN + ReLU.  A bf16 -> R2t[n][hw][64] bf16.
// LDS-transpose epilogue -> coalesced 16B stores.
__global__ __launch_bounds__(256, 2) void k2_mfma(
    const unsigned short* A, unsigned short* R2t,
    const unsigned short* Wt1f, const float* g, const float* bb) {
  __shared__ unsigned short sA[16384];          // 32 KB
  __shared__ unsigned short sOutT[64 * 72];     // 9 KB, [col][o] pad 72
  int n = blockIdx.x / 49;
  int hw0 = (blockIdx.x % 49) * 64;
  const unsigned short* Ab = A + n * 256 * 3136 + hw0;
  for (int idx = threadIdx.x; idx < 16384; idx += 256) {
    int c = idx >> 6, col = idx & 63;
    sA[(col * 256 + c) ^ ((col & 7) << 3)] = Ab[c * 3136 + col];
  }
  __syncthreads();
  int l = threadIdx.x & 63;
  int wv = threadIdx.x >> 6;                    // N-tile
  int l15 = l & 15, l4 = l >> 4;
  f32x4 acc[4];
#pragma unroll
  for (int m = 0; m < 4; m++) acc[m] = (f32x4){0.f, 0.f, 0.f, 0.f};
#pragma unroll
  for (int kc = 0; kc < 8; kc++) {
    int colt = wv * 16 + l15;
    int us = (colt * 256 + kc * 32 + (l4 << 3)) ^ ((colt & 7) << 3);
    bf16x8 b = *(const bf16x8*)(sA + us);
#pragma unroll
    for (int m = 0; m < 4; m++) {
      bf16x8 a = *(const bf16x8*)(Wt1f + (((kc * 4 + m) * 64 + l) << 3));
      acc[m] = __builtin_amdgcn_mfma_f32_16x16x32_bf16(a, b, acc[m], 0, 0, 0);
    }
  }
  int colw = wv * 16 + l15;
#pragma unroll
  for (int m = 0; m < 4; m++) {
#pragma unroll
    for (int r = 0; r < 4; r++) {
      int o = m * 16 + l4 * 4 + r;
      float v = fmaxf(fmaf(acc[m][r], g[o] * MSC_BNI, bb[o]), 0.f);
      sOutT[colw * 72 + o] = f2b(v);
    }
  }
  __syncthreads();
  // write out: 512 16B-chunks, coalesced
  for (int ch = threadIdx.x; ch < 512; ch += 256) {
    int col = ch >> 3, cg = ch & 7;
    bf16x8 v = *(const bf16x8*)(sOutT + col * 72 + cg * 8);
    *(bf16x8*)(R2t + (n * 3136 + hw0 + col) * 64 + cg * 8) = v;
  }
}

// K3: 1x1 conv 64->16 + BN + ReLU.  R2t bf16 -> Y fp32 [n][16][hw].
__global__ __launch_bounds__(256, 2) void k3_conv21(
    const unsigned short* R2t, float* Y,
    const float* w, const float* g, const float* bb) {
  int i = blockIdx.x * 256 + threadIdx.x;       // over 200,704
  int n = i / 3136;
  int hw = i - n * 3136;
  const unsigned short* Rb = R2t + (n * 3136 + hw) * 64;
  float creg[64];
#pragma unroll
  for (int gq = 0; gq < 8; gq++) {
    bf16x8 v = *(const bf16x8*)(Rb + gq * 8);
#pragma unroll
    for (int j = 0; j < 8; j++) creg[gq * 8 + j] = b2f((unsigned short)v[j]);
  }
  float* Yb = Y + n * 16 * 3136 + hw;
  for (int o = 0; o < 16; o++) {
    const float* wr = w + o * 64;               // uniform, contiguous
    float a0 = 0.f, a1 = 0.f, a2 = 0.f, a3 = 0.f;
#pragma unroll
    for (int c = 0; c < 16; c++) {
      a0 = fmaf(wr[4*c+0], creg[4*c+0], a0);
      a1 = fmaf(wr[4*c+1], creg[4*c+1], a1);
      a2 = fmaf(wr[4*c+2], creg[4*c+2], a2);
      a3 = fmaf(wr[4*c+3], creg[4*c+3], a3);
    }
    float acc = (a0 + a1) + (a2 + a3);
    Yb[o * 3136] = fmaxf(fmaf(acc, g[o] * MSC_BNI, bb[o]), 0.f);
  }
}

// K4: 7x7-displacement correlation /16 + BN + ReLU -> COt[n][hw][64] bf16 (pad 0).
__global__ __launch_bounds__(256, 2) void k4_corr(
    const float* Y, unsigned short* COt, const float* g, const float* bb) {
  __shared__ float sb[10][16][62];              // rows h0-3..h0+6, ch, cols -3..58
  int n = blockIdx.x / 14;
  int h0 = (blockIdx.x % 14) * 4;
  int t = n & 7;
  int n2 = (t < 7) ? n + 1 : n;
  const float* Yb = Y + n2 * 16 * 3136;
  for (int idx = threadIdx.x; idx < 9920; idx += 256) {
    int r = idx / 992;
    int rem = idx - r * 992;
    int ch = rem / 62;
    int cl = rem - ch * 62;
    int gr = h0 - 3 + r, gc = cl - 3;
    float v = 0.f;
    if (gr >= 0 && gr < 56 && gc >= 0 && gc < 56)
      v = Yb[ch * 3136 + gr * 56 + gc];
    sb[r][ch][cl] = v;
  }
  __syncthreads();
  int pos = threadIdx.x;
  if (pos < 224) {
    int hl = pos / 56, wcol = pos - (pos / 56) * 56;
    float a[16];
    const float* Ya = Y + n * 16 * 3136 + (h0 + hl) * 56 + wcol;
#pragma unroll
    for (int c = 0; c < 16; c++) a[c] = Ya[c * 3136];
    float corr[49];
    for (int di = 0; di < 7; di++) {
      for (int dj = 0; dj < 7; dj++) {
        float s = 0.f;
#pragma unroll
        for (int c = 0; c < 16; c++) s = fmaf(a[c], sb[hl + di][c][wcol + dj], s);
        int k = di * 7 + dj;
        corr[k] = fmaxf(fmaf(s * 0.0625f, g[k] * MSC_BNI, bb[k]), 0.f);
      }
    }
    unsigned short* Cp = COt + (n * 3136 + (h0 + hl) * 56 + wcol) * 64;
#pragma unroll
    for (int gq = 0; gq < 8; gq++) {
      bf16x8 pv;
#pragma unroll
      for (int j = 0; j < 8; j++) {
        int k = gq * 8 + j;
        pv[j] = (k < 49) ? (short)f2b(corr[k]) : (short)0;
      }
      *(bf16x8*)(Cp + gq * 8) = pv;
    }
  }
}

// K5: 1x1 conv 49->64 via MFMA (K padded 64) + BN + R2t-add + ReLU -> O2t bf16.
// B-fragments read DIRECTLY from COt global (no LDS).
__global__ __launch_bounds__(256, 2) void k5_mfma(
    const unsigned short* COt, const unsigned short* R2t, unsigned short* O2t,
    const unsigned short* Wt4f, const float* g, const float* bb) {
  int nblk = blockIdx.x / 49;
  int hw0 = (blockIdx.x % 49) * 64;
  int l = threadIdx.x & 63;
  int wv = threadIdx.x >> 6;                    // N-tile
  int l15 = l & 15, l4 = l >> 4;
  int col = hw0 + wv * 16 + l15;
  int base = (nblk * 3136 + col) * 64;
  f32x4 acc[4];
#pragma unroll
  for (int m = 0; m < 4; m++) acc[m] = (f32x4){0.f, 0.f, 0.f, 0.f};
#pragma unroll
  for (int kc = 0; kc < 2; kc++) {
    bf16x8 b = *(const bf16x8*)(COt + base + kc * 32 + l4 * 8);
#pragma unroll
    for (int m = 0; m < 4; m++) {
      bf16x8 a = *(const bf16x8*)(Wt4f + (((kc * 4 + m) * 64 + l) << 3));
      acc[m] = __builtin_amdgcn_mfma_f32_16x16x32_bf16(a, b, acc[m], 0, 0, 0);
    }
  }
#pragma unroll
  for (int m = 0; m < 4; m++) {
    ush4 rv = *(const ush4*)(R2t + base + m * 16 + l4 * 4);
    ush4 ov;
#pragma unroll
    for (int r = 0; r < 4; r++) {
      int o = m * 16 + l4 * 4 + r;
      float v = fmaxf(fmaf(acc[m][r], g[o] * MSC_BNI, bb[o]) + b2f(rv.v[r]), 0.f);
      ov.v[r] = f2b(v);
    }
    *(ush4*)(O2t + base + m * 16 + l4 * 4) = ov;
  }
}

// K6: 3x3 conv 64->64 via MFMA implicit GEMM + BN + ReLU + O2t -> C2t bf16.
// Staging: 16B loads from R2t + ds_write_b128 (swizzled). 
__global__ __launch_bounds__(256, 2) void k6_mfma(
    const unsigned short* R2t, const unsigned short* O2t, unsigned short* C2t,
    const unsigned short* Wt2f, const float* g2, const float* b2) {
  __shared__ unsigned short sIn[22272];         // 6*58*64, 44,544 B
  int n = blockIdx.x / 14;
  int h0 = (blockIdx.x % 14) * 4;
  const unsigned short* Rt = R2t + n * 3136 * 64;
  for (int ch = threadIdx.x; ch < 2784; ch += 256) {
    int rc = ch >> 3;                           // row*58 + col
    int cg = ch & 7;
    int row = rc / 58, col = rc - row * 58;
    int gr = h0 - 1 + row, gc = col - 1;
    bf16x8 v = (bf16x8){0, 0, 0, 0, 0, 0, 0, 0};
    if (gr >= 0 && gr < 56 && gc >= 0 && gc < 56)
      v = *(const bf16x8*)(Rt + (gr * 56 + gc) * 64 + cg * 8);
    *(bf16x8*)(sIn + rc * 64 + ((cg ^ (col & 7)) << 3)) = v;
  }
  __syncthreads();
  int l = threadIdx.x & 63;
  int wv = threadIdx.x >> 6;                    // 0..3
  int l15 = l & 15, l4 = l >> 4;
  f32x4 acc[4][4];
#pragma unroll
  for (int m = 0; m < 4; m++)
#pragma unroll
    for (int t = 0; t < 4; t++) acc[m][t] = (f32x4){0.f, 0.f, 0.f, 0.f};

  for (int tap = 0; tap < 9; tap++) {
    int ky = tap / 3;
    int kx = tap - ky * 3;
    for (int kc = 0; kc < 2; kc++) {
      bf16x8 a[4];
#pragma unroll
      for (int m = 0; m < 4; m++)
        a[m] = *(const bf16x8*)(Wt2f + ((((tap * 2 + kc) * 4 + m) * 64 + l) << 3));
#pragma unroll
      for (int t = 0; t < 4; t++) {
        int ct = wv * 4 + t;
        int rowt = ct >> 2, col0 = (ct & 3) << 4;
        int lcol = col0 + l15 + kx;
        if (lcol > 57) lcol = 57;               // discarded cols read padding
        int us = ((((rowt + ky) * 58 + lcol) * 64) + kc * 32 + (l4 << 3))
                 ^ ((lcol & 7) << 3);
        bf16x8 b = *(const bf16x8*)(sIn + us);
#pragma unroll
        for (int m = 0; m < 4; m++)
          acc[m][t] = __builtin_amdgcn_mfma_f32_16x16x32_bf16(a[m], b, acc[m][t], 0, 0, 0);
      }
    }
  }

#pragma unroll
  for (int t = 0; t < 4; t++) {
    int ct = wv * 4 + t;
    int rowt = ct >> 2, col0 = (ct & 3) << 4;
    int cc = col0 + l15;
    if (cc < 56) {
      int hw = (h0 + rowt) * 56 + cc;
      int base = (n * 3136 + hw) * 64;
#pragma unroll
      for (int m = 0; m < 4; m++) {
        ush4 o2 = *(const ush4*)(O2t + base + m * 16 + l4 * 4);
        ush4 ov;
#pragma unroll
        for (int r = 0; r < 4; r++) {
          int o = m * 16 + l4 * 4 + r;
          float v = fmaxf(fmaf(acc[m][t][r], g2[o] * MSC_BNI, b2[o]), 0.f)
                    + b2f(o2.v[r]);
          ov.v[r] = f2b(v);
        }
        *(ush4*)(C2t + base + m * 16 + l4 * 4) = ov;
      }
    }
  }
}

// K7: 1x1 conv 64->256 via MFMA GEMM + BN + x-residual + ReLU -> d_out fp32.
// B-fragments DIRECT from C2t global; LDS-transposed coalesced epilogue.
__global__ __launch_bounds__(256, 2) void k7_mfma(
    const unsigned short* C2t, const float* x, float* outp,
    const unsigned short* Wt3f, const float* g, const float* bb) {
  __shared__ float sOut[64 * 68];               // 17,408 B
  int n = blockIdx.x / 49;
  int hw0 = (blockIdx.x % 49) * 64;
  int l = threadIdx.x & 63;
  int wv = threadIdx.x >> 6;                    // 0..3
  int l15 = l & 15, l4 = l >> 4;
  f32x4 acc[4][4];
#pragma unroll
  for (int m = 0; m < 4; m++)
#pragma unroll
    for (int t = 0; t < 4; t++) acc[m][t] = (f32x4){0.f, 0.f, 0.f, 0.f};

#pragma unroll
  for (int kc = 0; kc < 2; kc++) {
    bf16x8 a[4];
#pragma unroll
    for (int m = 0; m < 4; m++)
      a[m] = *(const bf16x8*)(Wt3f + (((kc * 16 + wv * 4 + m) * 64 + l) << 3));
#pragma unroll
    for (int t = 0; t < 4; t++) {
      int colt = t * 16 + l15;
      bf16x8 b = *(const bf16x8*)(C2t + (n * 3136 + hw0 + colt) * 64 + kc * 32 + l4 * 8);
#pragma unroll
      for (int m = 0; m < 4; m++)
        acc[m][t] = __builtin_amdgcn_mfma_f32_16x16x32_bf16(a[m], b, acc[m][t], 0, 0, 0);
    }
  }

  // epilogue: 4 passes; pass m covers o = wv*64 + m*16 + [0,16) for wv 0..3.
  for (int m = 0; m < 4; m++) {
#pragma unroll
    for (int t = 0; t < 4; t++)
#pragma unroll
      for (int r = 0; r < 4; r++)
        sOut[(wv * 16 + l4 * 4 + r) * 68 + t * 16 + l15] = acc[m][t][r];
    __syncthreads();
#pragma unroll
    for (int s = 0; s < 4; s++) {
      int ro = (threadIdx.x >> 4) + s * 16;     // 0..63
      int o = (ro >> 4) * 64 + m * 16 + (ro & 15);
      int colq = (threadIdx.x & 15) * 4;
      float4 v = *(float4*)&sOut[ro * 68 + colq];
      int off = (n * 256 + o) * 3136 + hw0 + colq;
      float4 xv = *(const float4*)(x + off);
      float sg = g[o] * MSC_BNI, bo = bb[o];
      float4 ov;
      ov.x = fmaxf(fmaf(v.x, sg, bo) + xv.x, 0.f);
      ov.y = fmaxf(fmaf(v.y, sg, bo) + xv.y, 0.f);
      ov.z = fmaxf(fmaf(v.z, sg, bo) + xv.z, 0.f);
      ov.w = fmaxf(fmaf(v.w, sg, bo) + xv.w, 0.f);
      *(float4*)(outp + off) = ov;
    }
    __syncthreads();
  }
}

extern "C" void kernel_launch(void* const* d_in, const int* in_sizes, int n_in,
                              void* d_out, int out_size, void* d_ws, size_t ws_size,
                              hipStream_t stream) {
  const float* x        = (const float*)d_in[0];
  const float* w1       = (const float*)d_in[1];
  const float* w3       = (const float*)d_in[2];
  const float* w5       = (const float*)d_in[3];
  const float* w7       = (const float*)d_in[4];
  const float* w_conv1  = (const float*)d_in[5];
  const float* g1       = (const float*)d_in[6];
  const float* b1       = (const float*)d_in[7];
  const float* w_conv21 = (const float*)d_in[8];
  const float* g21      = (const float*)d_in[9];
  const float* b21      = (const float*)d_in[10];
  const float* g22      = (const float*)d_in[11];
  const float* b22      = (const float*)d_in[12];
  const float* w_conv22 = (const float*)d_in[13];
  const float* g23      = (const float*)d_in[14];
  const float* b23      = (const float*)d_in[15];
  const float* w_conv2  = (const float*)d_in[16];
  const float* g2       = (const float*)d_in[17];
  const float* b2       = (const float*)d_in[18];
  const float* w_conv3  = (const float*)d_in[19];
  const float* g3       = (const float*)d_in[20];
  const float* b3       = (const float*)d_in[21];

  // d_out (fp32, 205,520,896 B) scratch map (all dead before K7's rewrite):
  //   A    bf16 [0 .. 102,760,448)            K1 w, K2 r
  //   Y    fp32 [0 .. 12,845,056)             K3 w, K4 r   (A dead)
  //   COt  bf16 [12,845,056 .. 38,535,168)    K4 w, K5 r   [n][hw][64]
  //   O2t  bf16 [38,535,168 .. 64,225,280)    K5 w, K6 r   [n][hw][64]
  //   R2t  bf16 [103,563,264 .. 129,253,376)  K2 w; K3,K5,K6 r  [n][hw][64]
  //   Wt2f bf16 [134,217,728 .. +73,728)      K0 w, K6 r
  //   Wt1f bf16 [134,291,456 .. +32,768)      K0 w, K2 r
  //   Wt4f bf16 [134,324,224 .. +8,192)       K0 w, K5 r
  // d_ws:
  //   C2t  bf16 [0 .. 25,690,112)             K6 w, K7 r   [n][hw][64]
  //   Wt3f bf16 [25,690,112 .. +32,768)       K0 w, K7 r (K7 overwrites d_out)
  char* ob = (char*)d_out;
  char* ws = (char*)d_ws;
  unsigned short* A    = (unsigned short*)ob;
  float*          Yv   = (float*)ob;
  unsigned short* COt  = (unsigned short*)(ob + 12845056);
  unsigned short* O2t  = (unsigned short*)(ob + 38535168);
  unsigned short* R2t  = (unsigned short*)(ob + 103563264);
  unsigned short* Wt2f = (unsigned short*)(ob + 134217728);
  unsigned short* Wt1f = (unsigned short*)(ob + 134291456);
  unsigned short* Wt4f = (unsigned short*)(ob + 134324224);
  unsigned short* C2t  = (unsigned short*)ws;
  unsigned short* Wt3f = (unsigned short*)(ws + 25690112);

  k0_prep  <<<dim3(288),     dim3(256), 0, stream>>>(w_conv1, w_conv2, w_conv3, w_conv22,
                                                     Wt1f, Wt2f, Wt3f, Wt4f);
  k1_tconv <<<dim3(25088),   dim3(256), 0, stream>>>(x, A, w1, w3, w5, w7);
  k2_mfma  <<<dim3(64 * 49), dim3(256), 0, stream>>>(A, R2t, Wt1f, g1, b1);
  k3_conv21<<<dim3(784),     dim3(256), 0, stream>>>(R2t, Yv, w_conv21, g21, b21);
  k4_corr  <<<dim3(64 * 14), dim3(256), 0, stream>>>(Yv, COt, g22, b22);
  k5_mfma  <<<dim3(64 * 49), dim3(256), 0, stream>>>(COt, R2t, O2t, Wt4f, g23, b23);
  k6_mfma  <<<dim3(64 * 14), dim3(256), 0, stream>>>(R2t, O2t, C2t, Wt2f, g2, b2);
  k7_mfma  <<<dim3(64 * 49), dim3(256), 0, stream>>>(C2t, x, (float*)d_out, Wt3f, g3, b3);
}

// Round 16
// 285.604 us; speedup vs baseline: 8.6860x; 1.1137x over previous
//
#include <hip/hip_runtime.h>

// MsCorrBlock: B=8 T=8 C=256 PL=64 CR=16 H=W=56 HW=3136 NT=64 PS=7 KK=49
// Output dtype: FLOAT32 (205,520,896 B). BNI = 1/sqrt(1+1e-5).

#define MSC_BNI 0.9999950000374997f

typedef __attribute__((ext_vector_type(8))) short bf16x8;
typedef __attribute__((ext_vector_type(4))) float f32x4;
struct __align__(8) ush4 { unsigned short v[4]; };

static __device__ __forceinline__ float b2f(unsigned short h) {
  return __uint_as_float(((unsigned int)h) << 16);
}
static __device__ __forceinline__ unsigned short f2b(float f) {
  unsigned int u = __float_as_uint(f);
  u = u + 0x7FFFu + ((u >> 16) & 1u);   // round to nearest even
  return (unsigned short)(u >> 16);
}

// K0: pack bf16 MFMA A-fragments (convention validated rounds 11-15):
//   Wt2f [tap9][kc2][m4][lane64][e8]: w2[o=m*16+(l&15)][c=kc*32+(l>>4)*8+e][tap]
//   Wt3f [kc2][m16][lane64][e8]:      w3[o][c]
//   Wt1f [kc8][m4][lane64][e8]:       w1[o][c]
//   Wt4f [kc2][m4][lane64][e8]:       w22[o][c] (c>=49 -> 0)
__global__ __launch_bounds__(256) void k0_prep(
    const float* w1, const float* w2, const float* w3, const float* w22,
    unsigned short* Wt1f, unsigned short* Wt2f, unsigned short* Wt3f,
    unsigned short* Wt4f) {
  int idx = blockIdx.x * 256 + threadIdx.x;
  if (idx < 36864) {
    int j = idx;
    int e = j & 7;
    int lane = (j >> 3) & 63;
    int m = (j >> 9) & 3;
    int kc = (j >> 11) & 1;
    int tap = j >> 12;                       // 0..8
    int o = m * 16 + (lane & 15);
    int c = kc * 32 + (lane >> 4) * 8 + e;
    Wt2f[j] = f2b(w2[(o * 64 + c) * 9 + tap]);
  } else if (idx < 36864 + 16384) {
    int j = idx - 36864;
    int e = j & 7;
    int lane = (j >> 3) & 63;
    int m = (j >> 9) & 15;
    int kc = j >> 13;                        // 0..1
    int o = m * 16 + (lane & 15);
    int c = kc * 32 + (lane >> 4) * 8 + e;
    Wt3f[j] = f2b(w3[o * 64 + c]);
  } else if (idx < 36864 + 16384 + 16384) {
    int j = idx - 36864 - 16384;
    int e = j & 7;
    int lane = (j >> 3) & 63;
    int m = (j >> 9) & 3;
    int kc = j >> 11;                        // 0..7
    int o = m * 16 + (lane & 15);
    int c = kc * 32 + (lane >> 4) * 8 + e;
    Wt1f[j] = f2b(w1[o * 256 + c]);
  } else if (idx < 36864 + 16384 + 16384 + 4096) {
    int j = idx - 36864 - 16384 - 16384;
    int e = j & 7;
    int lane = (j >> 3) & 63;
    int m = (j >> 9) & 3;
    int kc = j >> 11;                        // 0..1
    int o = m * 16 + (lane & 15);
    int c = kc * 32 + (lane >> 4) * 8 + e;
    Wt4f[j] = (c < 49) ? f2b(w22[o * 49 + c]) : (unsigned short)0;
  }
}

// K12: FUSED temporal conv + 1x1 conv 256->64 (MFMA) + BN + ReLU -> R2t bf16.
// Block = (b, 32 hw cols). Per 32-c chunk: stage x fp32 -> tconv (registers)
// -> sA bf16 -> MFMA (wave = 2 t-frames x 4 M x 2 N). Eliminates the A tensor.
__global__ __launch_bounds__(256, 2) void k12_fused(
    const float* x, unsigned short* R2t, const unsigned short* Wt1f,
    const float* w1, const float* w3, const float* w5, const float* w7,
    const float* g, const float* bb) {
  __shared__ float sX[8 * 32 * 34];             // [t][col][c] pad34, 34,816 B
  __shared__ unsigned short sA[8 * 32 * 40];    // [t][col][c] pad40, 20,480 B
  int b = blockIdx.x / 98;
  int hw0 = (blockIdx.x % 98) * 32;
  int tid = threadIdx.x;
  int l = tid & 63, wv = tid >> 6;
  int l15 = l & 15, l4 = l >> 4;
  f32x4 acc[2][4][2];
#pragma unroll
  for (int tt = 0; tt < 2; tt++)
#pragma unroll
    for (int m = 0; m < 4; m++)
#pragma unroll
      for (int nt = 0; nt < 2; nt++) acc[tt][m][nt] = (f32x4){0.f, 0.f, 0.f, 0.f};

  int colp = tid & 31;
  int cbase = tid >> 5;                         // 0..7

  for (int kc8 = 0; kc8 < 8; kc8++) {
    int c0 = kc8 * 32;
    // stage x chunk: [t][col][c]
#pragma unroll
    for (int k = 0; k < 32; k++) {
      int idx = tid + k * 256;
      int col = idx & 31;
      int r = idx >> 5;                         // t*32 + c
      int t = r >> 5, c = r & 31;
      sX[(t * 32 + col) * 34 + c] =
          x[((b * 8 + t) * 256 + c0 + c) * 3136 + hw0 + col];
    }
    __syncthreads();
    // tconv: thread = (c,col) x4 pairs, all 8 t. Quarter q uniform per chunk.
    int q = kc8 >> 1;
#pragma unroll
    for (int p = 0; p < 4; p++) {
      int c = cbase + p * 8;
      int cq = (kc8 & 1) * 32 + c;              // channel index within quarter
      float wf[7];
#pragma unroll
      for (int k = 0; k < 7; k++) wf[k] = 0.f;
      if (q == 0) { wf[3] = w1[cq]; }
      else if (q == 1) { wf[2] = w3[cq*3]; wf[3] = w3[cq*3+1]; wf[4] = w3[cq*3+2]; }
      else if (q == 2) { wf[1] = w5[cq*5]; wf[2] = w5[cq*5+1]; wf[3] = w5[cq*5+2]; wf[4] = w5[cq*5+3]; wf[5] = w5[cq*5+4]; }
      else { wf[0] = w7[cq*7]; wf[1] = w7[cq*7+1]; wf[2] = w7[cq*7+2]; wf[3] = w7[cq*7+3]; wf[4] = w7[cq*7+4]; wf[5] = w7[cq*7+5]; wf[6] = w7[cq*7+6]; }
      float xin[8];
#pragma unroll
      for (int t = 0; t < 8; t++) xin[t] = sX[(t * 32 + colp) * 34 + c];
#pragma unroll
      for (int t = 0; t < 8; t++) {
        float a = 0.f;
#pragma unroll
        for (int d = -3; d <= 3; d++) {
          int ts = t + d;
          if (ts >= 0 && ts < 8) a = fmaf(wf[d + 3], xin[ts], a);
        }
        sA[(t * 32 + colp) * 40 + c] = f2b(a);
      }
    }
    __syncthreads();
    // GEMM: wave wv covers t = wv*2, wv*2+1
#pragma unroll
    for (int tt = 0; tt < 2; tt++) {
      int t = wv * 2 + tt;
#pragma unroll
      for (int nt = 0; nt < 2; nt++) {
        int colt = nt * 16 + l15;
        bf16x8 bfr = *(const bf16x8*)(sA + (t * 32 + colt) * 40 + l4 * 8);
#pragma unroll
        for (int m = 0; m < 4; m++) {
          bf16x8 a = *(const bf16x8*)(Wt1f + (((kc8 * 4 + m) * 64 + l) << 3));
          acc[tt][m][nt] = __builtin_amdgcn_mfma_f32_16x16x32_bf16(a, bfr, acc[tt][m][nt], 0, 0, 0);
        }
      }
    }
    __syncthreads();
  }
  // epilogue: per tt round, wave wv stages its t = wv*2+tt into sOutT[wv],
  // then all threads store coalesced 16B chunks.
  unsigned short* sOutT = sA;                   // [tb4][col32][o pad72]
  for (int tt = 0; tt < 2; tt++) {
#pragma unroll
    for (int m = 0; m < 4; m++)
#pragma unroll
      for (int nt = 0; nt < 2; nt++) {
        int col = nt * 16 + l15;
#pragma unroll
        for (int r = 0; r < 4; r++) {
          int o = m * 16 + l4 * 4 + r;
          float v = fmaxf(fmaf(acc[tt][m][nt][r], g[o] * MSC_BNI, bb[o]), 0.f);
          sOutT[(wv * 32 + col) * 72 + o] = f2b(v);
        }
      }
    __syncthreads();
#pragma unroll
    for (int k = 0; k < 4; k++) {
      int ch = tid + k * 256;                   // 1024 chunks of 16B
      int tb = ch >> 8, col = (ch >> 3) & 31, gg = ch & 7;
      int t = tb * 2 + tt;
      bf16x8 v = *(const bf16x8*)(sOutT + (tb * 32 + col) * 72 + gg * 8);
      *(bf16x8*)(R2t + ((b * 8 + t) * 3136 + hw0 + col) * 64 + gg * 8) = v;
    }
    __syncthreads();
  }
}

// K3: 1x1 conv 64->16 + BN + ReLU.  R2t bf16 -> Y fp32 [n][16][hw].
__global__ __launch_bounds__(256, 2) void k3_conv21(
    const unsigned short* R2t, float* Y,
    const float* w, const float* g, const float* bb) {
  int i = blockIdx.x * 256 + threadIdx.x;       // over 200,704
  int n = i / 3136;
  int hw = i - n * 3136;
  const unsigned short* Rb = R2t + (n * 3136 + hw) * 64;
  float creg[64];
#pragma unroll
  for (int gq = 0; gq < 8; gq++) {
    bf16x8 v = *(const bf16x8*)(Rb + gq * 8);
#pragma unroll
    for (int j = 0; j < 8; j++) creg[gq * 8 + j] = b2f((unsigned short)v[j]);
  }
  float* Yb = Y + n * 16 * 3136 + hw;
  for (int o = 0; o < 16; o++) {
    const float* wr = w + o * 64;               // uniform, contiguous
    float a0 = 0.f, a1 = 0.f, a2 = 0.f, a3 = 0.f;
#pragma unroll
    for (int c = 0; c < 16; c++) {
      a0 = fmaf(wr[4*c+0], creg[4*c+0], a0);
      a1 = fmaf(wr[4*c+1], creg[4*c+1], a1);
      a2 = fmaf(wr[4*c+2], creg[4*c+2], a2);
      a3 = fmaf(wr[4*c+3], creg[4*c+3], a3);
    }
    float acc = (a0 + a1) + (a2 + a3);
    Yb[o * 3136] = fmaxf(fmaf(acc, g[o] * MSC_BNI, bb[o]), 0.f);
  }
}

// K4: 7x7-displacement correlation /16 + BN + ReLU -> COt[n][hw][64] bf16 (pad 0).
__global__ __launch_bounds__(256, 2) void k4_corr(
    const float* Y, unsigned short* COt, const float* g, const float* bb) {
  __shared__ float sb[10][16][62];              // rows h0-3..h0+6, ch, cols -3..58
  int n = blockIdx.x / 14;
  int h0 = (blockIdx.x % 14) * 4;
  int t = n & 7;
  int n2 = (t < 7) ? n + 1 : n;
  const float* Yb = Y + n2 * 16 * 3136;
  for (int idx = threadIdx.x; idx < 9920; idx += 256) {
    int r = idx / 992;
    int rem = idx - r * 992;
    int ch = rem / 62;
    int cl = rem - ch * 62;
    int gr = h0 - 3 + r, gc = cl - 3;
    float v = 0.f;
    if (gr >= 0 && gr < 56 && gc >= 0 && gc < 56)
      v = Yb[ch * 3136 + gr * 56 + gc];
    sb[r][ch][cl] = v;
  }
  __syncthreads();
  int pos = threadIdx.x;
  if (pos < 224) {
    int hl = pos / 56, wcol = pos - (pos / 56) * 56;
    float a[16];
    const float* Ya = Y + n * 16 * 3136 + (h0 + hl) * 56 + wcol;
#pragma unroll
    for (int c = 0; c < 16; c++) a[c] = Ya[c * 3136];
    float corr[49];
    for (int di = 0; di < 7; di++) {
      for (int dj = 0; dj < 7; dj++) {
        float s = 0.f;
#pragma unroll
        for (int c = 0; c < 16; c++) s = fmaf(a[c], sb[hl + di][c][wcol + dj], s);
        int k = di * 7 + dj;
        corr[k] = fmaxf(fmaf(s * 0.0625f, g[k] * MSC_BNI, bb[k]), 0.f);
      }
    }
    unsigned short* Cp = COt + (n * 3136 + (h0 + hl) * 56 + wcol) * 64;
#pragma unroll
    for (int gq = 0; gq < 8; gq++) {
      bf16x8 pv;
#pragma unroll
      for (int j = 0; j < 8; j++) {
        int k = gq * 8 + j;
        pv[j] = (k < 49) ? (short)f2b(corr[k]) : (short)0;
      }
      *(bf16x8*)(Cp + gq * 8) = pv;
    }
  }
}

// K56: FUSED 3x3 conv (MFMA implicit GEMM) + BN + ReLU
//      + [1x1 conv 49->64 + BN + R2-residual + ReLU] recomputed in epilogue.
// Eliminates the O2t tensor. R2 residual comes from the staged sIn LDS.
__global__ __launch_bounds__(256, 2) void k56_mfma(
    const unsigned short* R2t, const unsigned short* COt, unsigned short* C2t,
    const unsigned short* Wt2f, const unsigned short* Wt4f,
    const float* g2, const float* b2, const float* g23, const float* b23) {
  __shared__ unsigned short sIn[22272];         // 6*58*64, 44,544 B
  int n = blockIdx.x / 14;
  int h0 = (blockIdx.x % 14) * 4;
  const unsigned short* Rt = R2t + n * 3136 * 64;
  for (int ch = threadIdx.x; ch < 2784; ch += 256) {
    int rc = ch >> 3;                           // row*58 + col
    int cg = ch & 7;
    int row = rc / 58, col = rc - row * 58;
    int gr = h0 - 1 + row, gc = col - 1;
    bf16x8 v = (bf16x8){0, 0, 0, 0, 0, 0, 0, 0};
    if (gr >= 0 && gr < 56 && gc >= 0 && gc < 56)
      v = *(const bf16x8*)(Rt + (gr * 56 + gc) * 64 + cg * 8);
    *(bf16x8*)(sIn + rc * 64 + ((cg ^ (col & 7)) << 3)) = v;
  }
  __syncthreads();
  int l = threadIdx.x & 63;
  int wv = threadIdx.x >> 6;                    // 0..3
  int l15 = l & 15, l4 = l >> 4;
  f32x4 acc[4][4];
#pragma unroll
  for (int m = 0; m < 4; m++)
#pragma unroll
    for (int t = 0; t < 4; t++) acc[m][t] = (f32x4){0.f, 0.f, 0.f, 0.f};

  for (int tap = 0; tap < 9; tap++) {
    int ky = tap / 3;
    int kx = tap - ky * 3;
    for (int kc = 0; kc < 2; kc++) {
      bf16x8 a[4];
#pragma unroll
      for (int m = 0; m < 4; m++)
        a[m] = *(const bf16x8*)(Wt2f + ((((tap * 2 + kc) * 4 + m) * 64 + l) << 3));
#pragma unroll
      for (int t = 0; t < 4; t++) {
        int ct = wv * 4 + t;
        int rowt = ct >> 2, col0 = (ct & 3) << 4;
        int lcol = col0 + l15 + kx;
        if (lcol > 57) lcol = 57;               // discarded cols read padding
        int us = ((((rowt + ky) * 58 + lcol) * 64) + kc * 32 + (l4 << 3))
                 ^ ((lcol & 7) << 3);
        bf16x8 b = *(const bf16x8*)(sIn + us);
#pragma unroll
        for (int m = 0; m < 4; m++)
          acc[m][t] = __builtin_amdgcn_mfma_f32_16x16x32_bf16(a[m], b, acc[m][t], 0, 0, 0);
      }
    }
  }

#pragma unroll
  for (int t = 0; t < 4; t++) {
    int ct = wv * 4 + t;
    int rowt = ct >> 2, col0 = (ct & 3) << 4;
    int cc = col0 + l15;
    int cc_cl = (cc < 56) ? cc : 55;
    int gbase = (n * 3136 + (h0 + rowt) * 56 + cc_cl) * 64;
    // k5 GEMM (exec-uniform, clamped addresses for discarded lanes)
    f32x4 acc2[4];
#pragma unroll
    for (int m = 0; m < 4; m++) acc2[m] = (f32x4){0.f, 0.f, 0.f, 0.f};
#pragma unroll
    for (int kc = 0; kc < 2; kc++) {
      bf16x8 bco = *(const bf16x8*)(COt + gbase + kc * 32 + l4 * 8);
#pragma unroll
      for (int m = 0; m < 4; m++) {
        bf16x8 a = *(const bf16x8*)(Wt4f + (((kc * 4 + m) * 64 + l) << 3));
        acc2[m] = __builtin_amdgcn_mfma_f32_16x16x32_bf16(a, bco, acc2[m], 0, 0, 0);
      }
    }
    if (cc < 56) {
      int rc = (rowt + 1) * 58 + cc + 1;        // center cell in sIn
#pragma unroll
      for (int m = 0; m < 4; m++) {
        int cg0 = 2 * m + (l4 >> 1);
        int us = rc * 64 + ((cg0 ^ ((cc + 1) & 7)) << 3) + (l4 & 1) * 4;
        ush4 rv = *(const ush4*)(sIn + us);
        ush4 ov;
#pragma unroll
        for (int r = 0; r < 4; r++) {
          int o = m * 16 + l4 * 4 + r;
          float o2 = fmaxf(fmaf(acc2[m][r], g23[o] * MSC_BNI, b23[o]) + b2f(rv.v[r]), 0.f);
          float v = fmaxf(fmaf(acc[m][t][r], g2[o] * MSC_BNI, b2[o]), 0.f) + o2;
          ov.v[r] = f2b(v);
        }
        *(ush4*)(C2t + gbase + m * 16 + l4 * 4) = ov;
      }
    }
  }
}

// K7: 1x1 conv 64->256 via MFMA GEMM + BN + x-residual + ReLU -> d_out fp32.
// B-fragments DIRECT from C2t global; LDS-transposed coalesced epilogue.
__global__ __launch_bounds__(256, 2) void k7_mfma(
    const unsigned short* C2t, const float* x, float* outp,
    const unsigned short* Wt3f, const float* g, const float* bb) {
  __shared__ float sOut[64 * 68];               // 17,408 B
  int n = blockIdx.x / 49;
  int hw0 = (blockIdx.x % 49) * 64;
  int l = threadIdx.x & 63;
  int wv = threadIdx.x >> 6;                    // 0..3
  int l15 = l & 15, l4 = l >> 4;
  f32x4 acc[4][4];
#pragma unroll
  for (int m = 0; m < 4; m++)
#pragma unroll
    for (int t = 0; t < 4; t++) acc[m][t] = (f32x4){0.f, 0.f, 0.f, 0.f};

#pragma unroll
  for (int kc = 0; kc < 2; kc++) {
    bf16x8 a[4];
#pragma unroll
    for (int m = 0; m < 4; m++)
      a[m] = *(const bf16x8*)(Wt3f + (((kc * 16 + wv * 4 + m) * 64 + l) << 3));
#pragma unroll
    for (int t = 0; t < 4; t++) {
      int colt = t * 16 + l15;
      bf16x8 b = *(const bf16x8*)(C2t + (n * 3136 + hw0 + colt) * 64 + kc * 32 + l4 * 8);
#pragma unroll
      for (int m = 0; m < 4; m++)
        acc[m][t] = __builtin_amdgcn_mfma_f32_16x16x32_bf16(a[m], b, acc[m][t], 0, 0, 0);
    }
  }

  // epilogue: 4 passes; pass m covers o = wv*64 + m*16 + [0,16) for wv 0..3.
  for (int m = 0; m < 4; m++) {
#pragma unroll
    for (int t = 0; t < 4; t++)
#pragma unroll
      for (int r = 0; r < 4; r++)
        sOut[(wv * 16 + l4 * 4 + r) * 68 + t * 16 + l15] = acc[m][t][r];
    __syncthreads();
#pragma unroll
    for (int s = 0; s < 4; s++) {
      int ro = (threadIdx.x >> 4) + s * 16;     // 0..63
      int o = (ro >> 4) * 64 + m * 16 + (ro & 15);
      int colq = (threadIdx.x & 15) * 4;
      float4 v = *(float4*)&sOut[ro * 68 + colq];
      int off = (n * 256 + o) * 3136 + hw0 + colq;
      float4 xv = *(const float4*)(x + off);
      float sg = g[o] * MSC_BNI, bo = bb[o];
      float4 ov;
      ov.x = fmaxf(fmaf(v.x, sg, bo) + xv.x, 0.f);
      ov.y = fmaxf(fmaf(v.y, sg, bo) + xv.y, 0.f);
      ov.z = fmaxf(fmaf(v.z, sg, bo) + xv.z, 0.f);
      ov.w = fmaxf(fmaf(v.w, sg, bo) + xv.w, 0.f);
      *(float4*)(outp + off) = ov;
    }
    __syncthreads();
  }
}

extern "C" void kernel_launch(void* const* d_in, const int* in_sizes, int n_in,
                              void* d_out, int out_size, void* d_ws, size_t ws_size,
                              hipStream_t stream) {
  const float* x        = (const float*)d_in[0];
  const float* w1       = (const float*)d_in[1];
  const float* w3       = (const float*)d_in[2];
  const float* w5       = (const float*)d_in[3];
  const float* w7       = (const float*)d_in[4];
  const float* w_conv1  = (const float*)d_in[5];
  const float* g1       = (const float*)d_in[6];
  const float* b1       = (const float*)d_in[7];
  const float* w_conv21 = (const float*)d_in[8];
  const float* g21      = (const float*)d_in[9];
  const float* b21      = (const float*)d_in[10];
  const float* g22      = (const float*)d_in[11];
  const float* b22      = (const float*)d_in[12];
  const float* w_conv22 = (const float*)d_in[13];
  const float* g23      = (const float*)d_in[14];
  const float* b23      = (const float*)d_in[15];
  const float* w_conv2  = (const float*)d_in[16];
  const float* g2       = (const float*)d_in[17];
  const float* b2       = (const float*)d_in[18];
  const float* w_conv3  = (const float*)d_in[19];
  const float* g3       = (const float*)d_in[20];
  const float* b3       = (const float*)d_in[21];

  // d_out (fp32, 205,520,896 B) scratch map (all dead before K7's rewrite):
  //   Y    fp32 [0 .. 12,845,056)             K3 w, K4 r
  //   COt  bf16 [12,845,056 .. 38,535,168)    K4 w, K56 r  [n][hw][64]
  //   R2t  bf16 [103,563,264 .. 129,253,376)  K12 w; K3,K56 r  [n][hw][64]
  //   Wt2f bf16 [134,217,728 .. +73,728)      K0 w, K56 r
  //   Wt1f bf16 [134,291,456 .. +32,768)      K0 w, K12 r
  //   Wt4f bf16 [134,324,224 .. +8,192)       K0 w, K56 r
  // d_ws:
  //   C2t  bf16 [0 .. 25,690,112)             K56 w, K7 r  [n][hw][64]
  //   Wt3f bf16 [25,690,112 .. +32,768)       K0 w, K7 r (K7 overwrites d_out)
  char* ob = (char*)d_out;
  char* ws = (char*)d_ws;
  float*          Yv   = (float*)ob;
  unsigned short* COt  = (unsigned short*)(ob + 12845056);
  unsigned short* R2t  = (unsigned short*)(ob + 103563264);
  unsigned short* Wt2f = (unsigned short*)(ob + 134217728);
  unsigned short* Wt1f = (unsigned short*)(ob + 134291456);
  unsigned short* Wt4f = (unsigned short*)(ob + 134324224);
  unsigned short* C2t  = (unsigned short*)ws;
  unsigned short* Wt3f = (unsigned short*)(ws + 25690112);

  k0_prep  <<<dim3(288),     dim3(256), 0, stream>>>(w_conv1, w_conv2, w_conv3, w_conv22,
                                                     Wt1f, Wt2f, Wt3f, Wt4f);
  k12_fused<<<dim3(8 * 98),  dim3(256), 0, stream>>>(x, R2t, Wt1f, w1, w3, w5, w7, g1, b1);
  k3_conv21<<<dim3(784),     dim3(256), 0, stream>>>(R2t, Yv, w_conv21, g21, b21);
  k4_corr  <<<dim3(64 * 14), dim3(256), 0, stream>>>(Yv, COt, g22, b22);
  k56_mfma <<<dim3(64 * 14), dim3(256), 0, stream>>>(R2t, COt, C2t, Wt2f, Wt4f, g2, b2, g23, b23);
  k7_mfma  <<<dim3(64 * 49), dim3(256), 0, stream>>>(C2t, x, (float*)d_out, Wt3f, g3, b3);
}

// Round 17
// 247.619 us; speedup vs baseline: 10.0184x; 1.1534x over previous
//
#include <hip/hip_runtime.h>

// MsCorrBlock: B=8 T=8 C=256 PL=64 CR=16 H=W=56 HW=3136 NT=64 PS=7 KK=49
// Output dtype: FLOAT32 (205,520,896 B). BNI = 1/sqrt(1+1e-5).

#define MSC_BNI 0.9999950000374997f

typedef __attribute__((ext_vector_type(8))) short bf16x8;
typedef __attribute__((ext_vector_type(4))) float f32x4;
struct __align__(8) ush4 { unsigned short v[4]; };

static __device__ __forceinline__ float b2f(unsigned short h) {
  return __uint_as_float(((unsigned int)h) << 16);
}
static __device__ __forceinline__ unsigned short f2b(float f) {
  unsigned int u = __float_as_uint(f);
  u = u + 0x7FFFu + ((u >> 16) & 1u);   // round to nearest even
  return (unsigned short)(u >> 16);
}

// K0: pack bf16 MFMA A-fragments (convention validated rounds 11-16):
//   Wt2f [tap9][kc2][m4][lane64][e8]: w2[o=m*16+(l&15)][c=kc*32+(l>>4)*8+e][tap]
//   Wt3f [kc2][m16][lane64][e8]:      w3[o][c]
//   Wt1f [kc8][m4][lane64][e8]:       w1[o][c]
//   Wt4f [kc2][m4][lane64][e8]:      w22[o][c] (c>=49 -> 0)
//   Wt5f [kc2][lane64][e8]:          w21[o=l&15][c=kc*32+(l>>4)*8+e]  (M=16)
__global__ __launch_bounds__(256) void k0_prep(
    const float* w1, const float* w2, const float* w3, const float* w22,
    const float* w21,
    unsigned short* Wt1f, unsigned short* Wt2f, unsigned short* Wt3f,
    unsigned short* Wt4f, unsigned short* Wt5f) {
  int idx = blockIdx.x * 256 + threadIdx.x;
  if (idx < 36864) {
    int j = idx;
    int e = j & 7;
    int lane = (j >> 3) & 63;
    int m = (j >> 9) & 3;
    int kc = (j >> 11) & 1;
    int tap = j >> 12;                       // 0..8
    int o = m * 16 + (lane & 15);
    int c = kc * 32 + (lane >> 4) * 8 + e;
    Wt2f[j] = f2b(w2[(o * 64 + c) * 9 + tap]);
  } else if (idx < 36864 + 16384) {
    int j = idx - 36864;
    int e = j & 7;
    int lane = (j >> 3) & 63;
    int m = (j >> 9) & 15;
    int kc = j >> 13;                        // 0..1
    int o = m * 16 + (lane & 15);
    int c = kc * 32 + (lane >> 4) * 8 + e;
    Wt3f[j] = f2b(w3[o * 64 + c]);
  } else if (idx < 36864 + 16384 + 16384) {
    int j = idx - 36864 - 16384;
    int e = j & 7;
    int lane = (j >> 3) & 63;
    int m = (j >> 9) & 3;
    int kc = j >> 11;                        // 0..7
    int o = m * 16 + (lane & 15);
    int c = kc * 32 + (lane >> 4) * 8 + e;
    Wt1f[j] = f2b(w1[o * 256 + c]);
  } else if (idx < 36864 + 16384 + 16384 + 4096) {
    int j = idx - 36864 - 16384 - 16384;
    int e = j & 7;
    int lane = (j >> 3) & 63;
    int m = (j >> 9) & 3;
    int kc = j >> 11;                        // 0..1
    int o = m * 16 + (lane & 15);
    int c = kc * 32 + (lane >> 4) * 8 + e;
    Wt4f[j] = (c < 49) ? f2b(w22[o * 49 + c]) : (unsigned short)0;
  } else if (idx < 36864 + 16384 + 16384 + 4096 + 1024) {
    int j = idx - 36864 - 16384 - 16384 - 4096;
    int e = j & 7;
    int lane = (j >> 3) & 63;
    int kc = j >> 9;                         // 0..1
    int o = lane & 15;
    int c = kc * 32 + (lane >> 4) * 8 + e;
    Wt5f[j] = f2b(w21[o * 64 + c]);
  }
}

// K12: FUSED temporal conv + 1x1 conv 256->64 (MFMA) + BN + ReLU -> R2t bf16,
//      + 1x1 conv 64->16 (MFMA from sOutT) + BN + ReLU -> Yt fp32 [n][hw][16].
// Block = (b, 32 hw cols). tconv direct global->registers (no sX staging).
__global__ __launch_bounds__(256, 3) void k12_fused(
    const float* x, unsigned short* R2t, float* Yt,
    const unsigned short* Wt1f, const unsigned short* Wt5f,
    const float* w1, const float* w3, const float* w5, const float* w7,
    const float* g, const float* bb, const float* g21, const float* b21) {
  __shared__ unsigned short sA[8 * 32 * 40];    // [t][col][c] pad40, 20,480 B
  int b = blockIdx.x / 98;
  int hw0 = (blockIdx.x % 98) * 32;
  int tid = threadIdx.x;
  int l = tid & 63, wv = tid >> 6;
  int l15 = l & 15, l4 = l >> 4;
  f32x4 acc[2][4][2];
#pragma unroll
  for (int tt = 0; tt < 2; tt++)
#pragma unroll
    for (int m = 0; m < 4; m++)
#pragma unroll
      for (int nt = 0; nt < 2; nt++) acc[tt][m][nt] = (f32x4){0.f, 0.f, 0.f, 0.f};

  int colp = tid & 31;
  int cbase = tid >> 5;                         // 0..7

  for (int kc8 = 0; kc8 < 8; kc8++) {
    int c0 = kc8 * 32;
    int q = kc8 >> 1;
    // tconv: thread = (c,colp) x4, all 8 t; direct from global.
#pragma unroll
    for (int p = 0; p < 4; p++) {
      int c = cbase + p * 8;
      int cq = (kc8 & 1) * 32 + c;              // channel index within quarter
      float wf[7];
#pragma unroll
      for (int k = 0; k < 7; k++) wf[k] = 0.f;
      if (q == 0) { wf[3] = w1[cq]; }
      else if (q == 1) { wf[2] = w3[cq*3]; wf[3] = w3[cq*3+1]; wf[4] = w3[cq*3+2]; }
      else if (q == 2) { wf[1] = w5[cq*5]; wf[2] = w5[cq*5+1]; wf[3] = w5[cq*5+2]; wf[4] = w5[cq*5+3]; wf[5] = w5[cq*5+4]; }
      else { wf[0] = w7[cq*7]; wf[1] = w7[cq*7+1]; wf[2] = w7[cq*7+2]; wf[3] = w7[cq*7+3]; wf[4] = w7[cq*7+4]; wf[5] = w7[cq*7+5]; wf[6] = w7[cq*7+6]; }
      const float* xb = x + ((size_t)(b * 8) * 256 + c0 + c) * 3136 + hw0 + colp;
      float xin[8];
#pragma unroll
      for (int t = 0; t < 8; t++) xin[t] = xb[t * 256 * 3136];
#pragma unroll
      for (int t = 0; t < 8; t++) {
        float a = 0.f;
#pragma unroll
        for (int d = -3; d <= 3; d++) {
          int ts = t + d;
          if (ts >= 0 && ts < 8) a = fmaf(wf[d + 3], xin[ts], a);
        }
        sA[(t * 32 + colp) * 40 + c] = f2b(a);
      }
    }
    __syncthreads();
    // GEMM: wave wv covers t = wv*2, wv*2+1
#pragma unroll
    for (int tt = 0; tt < 2; tt++) {
      int t = wv * 2 + tt;
#pragma unroll
      for (int nt = 0; nt < 2; nt++) {
        int colt = nt * 16 + l15;
        bf16x8 bfr = *(const bf16x8*)(sA + (t * 32 + colt) * 40 + l4 * 8);
#pragma unroll
        for (int m = 0; m < 4; m++) {
          bf16x8 a = *(const bf16x8*)(Wt1f + (((kc8 * 4 + m) * 64 + l) << 3));
          acc[tt][m][nt] = __builtin_amdgcn_mfma_f32_16x16x32_bf16(a, bfr, acc[tt][m][nt], 0, 0, 0);
        }
      }
    }
    __syncthreads();
  }
  // epilogue per tt: sOutT (reuse sA) holds [tb4][col32][o pad72] bf16 R2.
  unsigned short* sOutT = sA;
  for (int tt = 0; tt < 2; tt++) {
#pragma unroll
    for (int m = 0; m < 4; m++)
#pragma unroll
      for (int nt = 0; nt < 2; nt++) {
        int col = nt * 16 + l15;
#pragma unroll
        for (int r = 0; r < 4; r++) {
          int o = m * 16 + l4 * 4 + r;
          float v = fmaxf(fmaf(acc[tt][m][nt][r], g[o] * MSC_BNI, bb[o]), 0.f);
          sOutT[(wv * 32 + col) * 72 + o] = f2b(v);
        }
      }
    __syncthreads();
    // R2t coalesced stores
#pragma unroll
    for (int k = 0; k < 4; k++) {
      int ch = tid + k * 256;                   // 1024 chunks of 16B
      int tb = ch >> 8, col = (ch >> 3) & 31, gg = ch & 7;
      int t = tb * 2 + tt;
      bf16x8 v = *(const bf16x8*)(sOutT + (tb * 32 + col) * 72 + gg * 8);
      *(bf16x8*)(R2t + (((size_t)(b * 8 + t) * 3136) + hw0 + col) * 64 + gg * 8) = v;
    }
    // fused k3: Y = relu(bn21(W21 . R2)), wave wv handles its own t-frame.
    {
      int t = wv * 2 + tt;
#pragma unroll
      for (int ct2 = 0; ct2 < 2; ct2++) {
        f32x4 a5 = (f32x4){0.f, 0.f, 0.f, 0.f};
#pragma unroll
        for (int kc = 0; kc < 2; kc++) {
          bf16x8 bfr = *(const bf16x8*)(sOutT + (wv * 32 + ct2 * 16 + l15) * 72 + kc * 32 + l4 * 8);
          bf16x8 a = *(const bf16x8*)(Wt5f + ((kc * 64 + l) << 3));
          a5 = __builtin_amdgcn_mfma_f32_16x16x32_bf16(a, bfr, a5, 0, 0, 0);
        }
        int hw = hw0 + ct2 * 16 + l15;
        float4 yv;
        {
          int o0 = l4 * 4;
          yv.x = fmaxf(fmaf(a5[0], g21[o0+0] * MSC_BNI, b21[o0+0]), 0.f);
          yv.y = fmaxf(fmaf(a5[1], g21[o0+1] * MSC_BNI, b21[o0+1]), 0.f);
          yv.z = fmaxf(fmaf(a5[2], g21[o0+2] * MSC_BNI, b21[o0+2]), 0.f);
          yv.w = fmaxf(fmaf(a5[3], g21[o0+3] * MSC_BNI, b21[o0+3]), 0.f);
        }
        *(float4*)(Yt + (((size_t)(b * 8 + t) * 3136) + hw) * 16 + l4 * 4) = yv;
      }
    }
    __syncthreads();
  }
}

// K4: 7x7-displacement correlation /16 + BN + ReLU -> COt[n][hw][64] bf16.
// Yt layout [n][hw][16] fp32: vectorized staging + ds_read_b128 inner loop.
__global__ __launch_bounds__(256, 2) void k4_corr(
    const float* Yt, unsigned short* COt, const float* g, const float* bb) {
  __shared__ float sb[10 * 62 * 20];            // [r][cl][c pad20], 49,600 B
  int n = blockIdx.x / 14;
  int h0 = (blockIdx.x % 14) * 4;
  int t = n & 7;
  int n2 = (t < 7) ? n + 1 : n;
  const float* Yb = Yt + (size_t)n2 * 3136 * 16;
  for (int idx = threadIdx.x; idx < 2480; idx += 256) {
    int c4 = idx & 3;
    int pix = idx >> 2;                         // r*62 + cl
    int r = pix / 62, cl = pix - r * 62;
    int gr = h0 - 3 + r, gc = cl - 3;
    float4 v = make_float4(0.f, 0.f, 0.f, 0.f);
    if (gr >= 0 && gr < 56 && gc >= 0 && gc < 56)
      v = *(const float4*)(Yb + (gr * 56 + gc) * 16 + c4 * 4);
    *(float4*)&sb[(r * 62 + cl) * 20 + c4 * 4] = v;
  }
  __syncthreads();
  int pos = threadIdx.x;
  if (pos < 224) {
    int hl = pos / 56, wcol = pos - (pos / 56) * 56;
    const float* Ya = Yt + ((size_t)n * 3136 + (h0 + hl) * 56 + wcol) * 16;
    float4 a0 = *(const float4*)(Ya + 0);
    float4 a1 = *(const float4*)(Ya + 4);
    float4 a2 = *(const float4*)(Ya + 8);
    float4 a3 = *(const float4*)(Ya + 12);
    float corr[49];
    for (int di = 0; di < 7; di++) {
      for (int dj = 0; dj < 7; dj++) {
        const float* sp = &sb[((hl + di) * 62 + wcol + dj) * 20];
        float4 b0 = *(const float4*)(sp + 0);
        float4 b1 = *(const float4*)(sp + 4);
        float4 b2 = *(const float4*)(sp + 8);
        float4 b3 = *(const float4*)(sp + 12);
        float s = 0.f;
        s = fmaf(a0.x, b0.x, s); s = fmaf(a0.y, b0.y, s);
        s = fmaf(a0.z, b0.z, s); s = fmaf(a0.w, b0.w, s);
        s = fmaf(a1.x, b1.x, s); s = fmaf(a1.y, b1.y, s);
        s = fmaf(a1.z, b1.z, s); s = fmaf(a1.w, b1.w, s);
        s = fmaf(a2.x, b2.x, s); s = fmaf(a2.y, b2.y, s);
        s = fmaf(a2.z, b2.z, s); s = fmaf(a2.w, b2.w, s);
        s = fmaf(a3.x, b3.x, s); s = fmaf(a3.y, b3.y, s);
        s = fmaf(a3.z, b3.z, s); s = fmaf(a3.w, b3.w, s);
        int k = di * 7 + dj;
        corr[k] = fmaxf(fmaf(s * 0.0625f, g[k] * MSC_BNI, bb[k]), 0.f);
      }
    }
    unsigned short* Cp = COt + ((size_t)n * 3136 + (h0 + hl) * 56 + wcol) * 64;
#pragma unroll
    for (int gq = 0; gq < 8; gq++) {
      bf16x8 pv;
#pragma unroll
      for (int j = 0; j < 8; j++) {
        int k = gq * 8 + j;
        pv[j] = (k < 49) ? (short)f2b(corr[k]) : (short)0;
      }
      *(bf16x8*)(Cp + gq * 8) = pv;
    }
  }
}

// K56: FUSED 3x3 conv (MFMA implicit GEMM) + BN + ReLU
//      + [1x1 conv 49->64 + BN + R2-residual + ReLU] recomputed in epilogue.
__global__ __launch_bounds__(256, 2) void k56_mfma(
    const unsigned short* R2t, const unsigned short* COt, unsigned short* C2t,
    const unsigned short* Wt2f, const unsigned short* Wt4f,
    const float* g2, const float* b2, const float* g23, const float* b23) {
  __shared__ unsigned short sIn[22272];         // 6*58*64, 44,544 B
  int n = blockIdx.x / 14;
  int h0 = (blockIdx.x % 14) * 4;
  const unsigned short* Rt = R2t + (size_t)n * 3136 * 64;
  for (int ch = threadIdx.x; ch < 2784; ch += 256) {
    int rc = ch >> 3;                           // row*58 + col
    int cg = ch & 7;
    int row = rc / 58, col = rc - row * 58;
    int gr = h0 - 1 + row, gc = col - 1;
    bf16x8 v = (bf16x8){0, 0, 0, 0, 0, 0, 0, 0};
    if (gr >= 0 && gr < 56 && gc >= 0 && gc < 56)
      v = *(const bf16x8*)(Rt + (gr * 56 + gc) * 64 + cg * 8);
    *(bf16x8*)(sIn + rc * 64 + ((cg ^ (col & 7)) << 3)) = v;
  }
  __syncthreads();
  int l = threadIdx.x & 63;
  int wv = threadIdx.x >> 6;                    // 0..3
  int l15 = l & 15, l4 = l >> 4;
  f32x4 acc[4][4];
#pragma unroll
  for (int m = 0; m < 4; m++)
#pragma unroll
    for (int t = 0; t < 4; t++) acc[m][t] = (f32x4){0.f, 0.f, 0.f, 0.f};

  for (int tap = 0; tap < 9; tap++) {
    int ky = tap / 3;
    int kx = tap - ky * 3;
    for (int kc = 0; kc < 2; kc++) {
      bf16x8 a[4];
#pragma unroll
      for (int m = 0; m < 4; m++)
        a[m] = *(const bf16x8*)(Wt2f + ((((tap * 2 + kc) * 4 + m) * 64 + l) << 3));
#pragma unroll
      for (int t = 0; t < 4; t++) {
        int ct = wv * 4 + t;
        int rowt = ct >> 2, col0 = (ct & 3) << 4;
        int lcol = col0 + l15 + kx;
        if (lcol > 57) lcol = 57;               // discarded cols read padding
        int us = ((((rowt + ky) * 58 + lcol) * 64) + kc * 32 + (l4 << 3))
                 ^ ((lcol & 7) << 3);
        bf16x8 b = *(const bf16x8*)(sIn + us);
#pragma unroll
        for (int m = 0; m < 4; m++)
          acc[m][t] = __builtin_amdgcn_mfma_f32_16x16x32_bf16(a[m], b, acc[m][t], 0, 0, 0);
      }
    }
  }

#pragma unroll
  for (int t = 0; t < 4; t++) {
    int ct = wv * 4 + t;
    int rowt = ct >> 2, col0 = (ct & 3) << 4;
    int cc = col0 + l15;
    int cc_cl = (cc < 56) ? cc : 55;
    int gbase = ((int)(n * 3136) + (h0 + rowt) * 56 + cc_cl) * 64;
    // k5 GEMM (exec-uniform, clamped addresses for discarded lanes)
    f32x4 acc2[4];
#pragma unroll
    for (int m = 0; m < 4; m++) acc2[m] = (f32x4){0.f, 0.f, 0.f, 0.f};
#pragma unroll
    for (int kc = 0; kc < 2; kc++) {
      bf16x8 bco = *(const bf16x8*)(COt + gbase + kc * 32 + l4 * 8);
#pragma unroll
      for (int m = 0; m < 4; m++) {
        bf16x8 a = *(const bf16x8*)(Wt4f + (((kc * 4 + m) * 64 + l) << 3));
        acc2[m] = __builtin_amdgcn_mfma_f32_16x16x32_bf16(a, bco, acc2[m], 0, 0, 0);
      }
    }
    if (cc < 56) {
      int rc = (rowt + 1) * 58 + cc + 1;        // center cell in sIn
#pragma unroll
      for (int m = 0; m < 4; m++) {
        int cg0 = 2 * m + (l4 >> 1);
        int us = rc * 64 + ((cg0 ^ ((cc + 1) & 7)) << 3) + (l4 & 1) * 4;
        ush4 rv = *(const ush4*)(sIn + us);
        ush4 ov;
#pragma unroll
        for (int r = 0; r < 4; r++) {
          int o = m * 16 + l4 * 4 + r;
          float o2 = fmaxf(fmaf(acc2[m][r], g23[o] * MSC_BNI, b23[o]) + b2f(rv.v[r]), 0.f);
          float v = fmaxf(fmaf(acc[m][t][r], g2[o] * MSC_BNI, b2[o]), 0.f) + o2;
          ov.v[r] = f2b(v);
        }
        *(ush4*)(C2t + gbase + m * 16 + l4 * 4) = ov;
      }
    }
  }
}

// K7: 1x1 conv 64->256 via MFMA GEMM + BN + x-residual + ReLU -> d_out fp32.
// B-fragments DIRECT from C2t global; LDS-transposed coalesced epilogue.
__global__ __launch_bounds__(256, 3) void k7_mfma(
    const unsigned short* C2t, const float* x, float* outp,
    const unsigned short* Wt3f, const float* g, const float* bb) {
  __shared__ float sOut[64 * 68];               // 17,408 B
  int n = blockIdx.x / 49;
  int hw0 = (blockIdx.x % 49) * 64;
  int l = threadIdx.x & 63;
  int wv = threadIdx.x >> 6;                    // 0..3
  int l15 = l & 15, l4 = l >> 4;
  f32x4 acc[4][4];
#pragma unroll
  for (int m = 0; m < 4; m++)
#pragma unroll
    for (int t = 0; t < 4; t++) acc[m][t] = (f32x4){0.f, 0.f, 0.f, 0.f};

#pragma unroll
  for (int kc = 0; kc < 2; kc++) {
    bf16x8 a[4];
#pragma unroll
    for (int m = 0; m < 4; m++)
      a[m] = *(const bf16x8*)(Wt3f + (((kc * 16 + wv * 4 + m) * 64 + l) << 3));
#pragma unroll
    for (int t = 0; t < 4; t++) {
      int colt = t * 16 + l15;
      bf16x8 b = *(const bf16x8*)(C2t + ((size_t)n * 3136 + hw0 + colt) * 64 + kc * 32 + l4 * 8);
#pragma unroll
      for (int m = 0; m < 4; m++)
        acc[m][t] = __builtin_amdgcn_mfma_f32_16x16x32_bf16(a[m], b, acc[m][t], 0, 0, 0);
    }
  }

  // epilogue: 4 passes; pass m covers o = wv*64 + m*16 + [0,16) for wv 0..3.
  for (int m = 0; m < 4; m++) {
#pragma unroll
    for (int t = 0; t < 4; t++)
#pragma unroll
      for (int r = 0; r < 4; r++)
        sOut[(wv * 16 + l4 * 4 + r) * 68 + t * 16 + l15] = acc[m][t][r];
    __syncthreads();
#pragma unroll
    for (int s = 0; s < 4; s++) {
      int ro = (threadIdx.x >> 4) + s * 16;     // 0..63
      int o = (ro >> 4) * 64 + m * 16 + (ro & 15);
      int colq = (threadIdx.x & 15) * 4;
      float4 v = *(float4*)&sOut[ro * 68 + colq];
      int off = (n * 256 + o) * 3136 + hw0 + colq;
      float4 xv = *(const float4*)(x + off);
      float sg = g[o] * MSC_BNI, bo = bb[o];
      float4 ov;
      ov.x = fmaxf(fmaf(v.x, sg, bo) + xv.x, 0.f);
      ov.y = fmaxf(fmaf(v.y, sg, bo) + xv.y, 0.f);
      ov.z = fmaxf(fmaf(v.z, sg, bo) + xv.z, 0.f);
      ov.w = fmaxf(fmaf(v.w, sg, bo) + xv.w, 0.f);
      *(float4*)(outp + off) = ov;
    }
    __syncthreads();
  }
}

extern "C" void kernel_launch(void* const* d_in, const int* in_sizes, int n_in,
                              void* d_out, int out_size, void* d_ws, size_t ws_size,
                              hipStream_t stream) {
  const float* x        = (const float*)d_in[0];
  const float* w1       = (const float*)d_in[1];
  const float* w3       = (const float*)d_in[2];
  const float* w5       = (const float*)d_in[3];
  const float* w7       = (const float*)d_in[4];
  const float* w_conv1  = (const float*)d_in[5];
  const float* g1       = (const float*)d_in[6];
  const float* b1       = (const float*)d_in[7];
  const float* w_conv21 = (const float*)d_in[8];
  const float* g21      = (const float*)d_in[9];
  const float* b21      = (const float*)d_in[10];
  const float* g22      = (const float*)d_in[11];
  const float* b22      = (const float*)d_in[12];
  const float* w_conv22 = (const float*)d_in[13];
  const float* g23      = (const float*)d_in[14];
  const float* b23      = (const float*)d_in[15];
  const float* w_conv2  = (const float*)d_in[16];
  const float* g2       = (const float*)d_in[17];
  const float* b2       = (const float*)d_in[18];
  const float* w_conv3  = (const float*)d_in[19];
  const float* g3       = (const float*)d_in[20];
  const float* b3       = (const float*)d_in[21];

  // d_out (fp32, 205,520,896 B) scratch map (all dead before K7's rewrite):
  //   Yt   fp32 [0 .. 12,845,056)             K12 w, K4 r  [n][hw][16]
  //   COt  bf16 [12,845,056 .. 38,535,168)    K4 w, K56 r  [n][hw][64]
  //   R2t  bf16 [103,563,264 .. 129,253,376)  K12 w; K56 r [n][hw][64]
  //   Wt2f bf16 [134,217,728 .. +73,728)      K0 w, K56 r
  //   Wt1f bf16 [134,291,456 .. +32,768)      K0 w, K12 r
  //   Wt4f bf16 [134,324,224 .. +8,192)       K0 w, K56 r
  //   Wt5f bf16 [134,332,416 .. +2,048)       K0 w, K12 r
  // d_ws:
  //   C2t  bf16 [0 .. 25,690,112)             K56 w, K7 r  [n][hw][64]
  //   Wt3f bf16 [25,690,112 .. +32,768)       K0 w, K7 r (K7 overwrites d_out)
  char* ob = (char*)d_out;
  char* ws = (char*)d_ws;
  float*          Yt   = (float*)ob;
  unsigned short* COt  = (unsigned short*)(ob + 12845056);
  unsigned short* R2t  = (unsigned short*)(ob + 103563264);
  unsigned short* Wt2f = (unsigned short*)(ob + 134217728);
  unsigned short* Wt1f = (unsigned short*)(ob + 134291456);
  unsigned short* Wt4f = (unsigned short*)(ob + 134324224);
  unsigned short* Wt5f = (unsigned short*)(ob + 134332416);
  unsigned short* C2t  = (unsigned short*)ws;
  unsigned short* Wt3f = (unsigned short*)(ws + 25690112);

  k0_prep  <<<dim3(292),     dim3(256), 0, stream>>>(w_conv1, w_conv2, w_conv3, w_conv22,
                                                     w_conv21, Wt1f, Wt2f, Wt3f, Wt4f, Wt5f);
  k12_fused<<<dim3(8 * 98),  dim3(256), 0, stream>>>(x, R2t, Yt, Wt1f, Wt5f,
                                                     w1, w3, w5, w7, g1, b1, g21, b21);
  k4_corr  <<<dim3(64 * 14), dim3(256), 0, stream>>>(Yt, COt, g22, b22);
  k56_mfma <<<dim3(64 * 14), dim3(256), 0, stream>>>(R2t, COt, C2t, Wt2f, Wt4f, g2, b2, g23, b23);
  k7_mfma  <<<dim3(64 * 49), dim3(256), 0, stream>>>(C2t, x, (float*)d_out, Wt3f, g3, b3);
}